// Round 1
// baseline (767.872 us; speedup 1.0000x reference)
//
#include <hip/hip_runtime.h>
#include <math.h>

typedef unsigned short u16;

constexpr int cB = 2;
constexpr int cS = 1024;
constexpr int cH = 1024;
constexpr int cNH = 16;
constexpr int cHD = 64;
constexpr int cW = 4;
constexpr int cL = (cW + 1) * cS; // 5120
constexpr float cEPS = 1e-5f;

typedef short s16x8 __attribute__((ext_vector_type(8)));   // 8 bf16 (4 VGPRs)
typedef float f32x4 __attribute__((ext_vector_type(4)));   // MFMA C/D

__device__ __forceinline__ float u2f(u16 u) {
  union { unsigned int i; float f; } x; x.i = ((unsigned int)u) << 16; return x.f;
}
__device__ __forceinline__ u16 f2u(float f) {
  union { float f; unsigned int i; } x; x.f = f;
  unsigned int i = x.i;
  i += 0x7fffu + ((i >> 16) & 1u); // RNE
  return (u16)(i >> 16);
}
__device__ __forceinline__ s16x8 ld_frag(const u16* p) {
  uint4 v = *(const uint4*)p;
  union { uint4 u; s16x8 s; } c; c.u = v; return c.s;
}
__device__ __forceinline__ s16x8 u4_frag(uint4 v) {
  union { uint4 u; s16x8 s; } c; c.u = v; return c.s;
}

// ---------------- LayerNorm f32 -> f32 (final LN) ----------------
__global__ __launch_bounds__(256) void ln_f32(
    const float* __restrict__ src, float* __restrict__ dst,
    const float* __restrict__ scale, const float* __restrict__ bias)
{
  int r = blockIdx.x;
  int t = threadIdx.x;
  const float* sp = src + (size_t)r * cH;
  float4 x = ((const float4*)sp)[t];
  float s1 = x.x + x.y + x.z + x.w;
  float s2 = x.x * x.x + x.y * x.y + x.z * x.z + x.w * x.w;
  #pragma unroll
  for (int off = 32; off > 0; off >>= 1) {
    s1 += __shfl_down(s1, off);
    s2 += __shfl_down(s2, off);
  }
  __shared__ float w1[4], w2[4];
  __shared__ float stat[2];
  int wid = t >> 6, lid = t & 63;
  if (lid == 0) { w1[wid] = s1; w2[wid] = s2; }
  __syncthreads();
  if (t == 0) {
    float a = w1[0] + w1[1] + w1[2] + w1[3];
    float b = w2[0] + w2[1] + w2[2] + w2[3];
    float mu = a * (1.f / cH);
    float var = b * (1.f / cH) - mu * mu;
    if (var < 0.f) var = 0.f;
    stat[0] = mu; stat[1] = rsqrtf(var + cEPS);
  }
  __syncthreads();
  float mu = stat[0], rs = stat[1];
  int h0 = t * 4;
  float4 sc = *(const float4*)(scale + h0);
  float4 bi = *(const float4*)(bias + h0);
  float4 o;
  o.x = (x.x - mu) * rs * sc.x + bi.x;
  o.y = (x.y - mu) * rs * sc.y + bi.y;
  o.z = (x.z - mu) * rs * sc.z + bi.z;
  o.w = (x.w - mu) * rs * sc.w + bi.w;
  *(float4*)(dst + (size_t)r * cH + h0) = o;
}

// ---------------- LayerNorm f32 -> bf16 into kvin tail ----------------
__global__ __launch_bounds__(256) void ln_bf16(
    const float* __restrict__ src, u16* __restrict__ kvin,
    const float* __restrict__ scale, const float* __restrict__ bias)
{
  int r = blockIdx.x;            // 0..cB*cS-1
  int t = threadIdx.x;
  const float* sp = src + (size_t)r * cH;
  float4 x = ((const float4*)sp)[t];
  float s1 = x.x + x.y + x.z + x.w;
  float s2 = x.x * x.x + x.y * x.y + x.z * x.z + x.w * x.w;
  #pragma unroll
  for (int off = 32; off > 0; off >>= 1) {
    s1 += __shfl_down(s1, off);
    s2 += __shfl_down(s2, off);
  }
  __shared__ float w1[4], w2[4];
  __shared__ float stat[2];
  int wid = t >> 6, lid = t & 63;
  if (lid == 0) { w1[wid] = s1; w2[wid] = s2; }
  __syncthreads();
  if (t == 0) {
    float a = w1[0] + w1[1] + w1[2] + w1[3];
    float b = w2[0] + w2[1] + w2[2] + w2[3];
    float mu = a * (1.f / cH);
    float var = b * (1.f / cH) - mu * mu;
    if (var < 0.f) var = 0.f;
    stat[0] = mu; stat[1] = rsqrtf(var + cEPS);
  }
  __syncthreads();
  float mu = stat[0], rs = stat[1];
  int h0 = t * 4;
  float4 sc = *(const float4*)(scale + h0);
  float4 bi = *(const float4*)(bias + h0);
  int b = r >> 10, s = r & (cS - 1);
  u16* dp = kvin + ((size_t)(b * cL + cW * cS + s)) * cH + h0;
  ushort4 o; u16* op = (u16*)&o;
  op[0] = f2u((x.x - mu) * rs * sc.x + bi.x);
  op[1] = f2u((x.y - mu) * rs * sc.y + bi.y);
  op[2] = f2u((x.z - mu) * rs * sc.z + bi.z);
  op[3] = f2u((x.w - mu) * rs * sc.w + bi.w);
  *(ushort4*)dp = o;
}

// -------- cache f32 [W,B,S,H] -> kvin bf16 [B, w*S+s, H] --------
__global__ __launch_bounds__(256) void cache2kv(const float* __restrict__ cache,
                                                u16* __restrict__ kvin) {
  int blk = blockIdx.x;          // cB*cW*cS = 8192
  int b = blk >> 12, w = (blk >> 10) & 3, s = blk & 1023;
  const float* src = cache + ((size_t)((w * cB + b) * cS + s)) * cH;
  u16* dst = kvin + ((size_t)(b * cL + w * cS + s)) * cH;
  int t = threadIdx.x;
  float4 v = *(const float4*)(src + t * 4);
  ushort4 o; u16* op = (u16*)&o;
  op[0] = f2u(v.x); op[1] = f2u(v.y); op[2] = f2u(v.z); op[3] = f2u(v.w);
  *(ushort4*)(dst + t * 4) = o;
}

// -------- weight transpose: W f32 [k][n] -> Wt bf16 [n][k], 4 matrices --------
__global__ __launch_bounds__(256) void wtrans(
    const float* __restrict__ W0, const float* __restrict__ W1,
    const float* __restrict__ W2, const float* __restrict__ W3,
    u16* __restrict__ Wt)
{
  __shared__ float tile[32][33];
  int mat = blockIdx.z;
  const float* W = (mat == 0) ? W0 : (mat == 1) ? W1 : (mat == 2) ? W2 : W3;
  u16* out = Wt + (size_t)mat * cH * cH;
  int k0 = blockIdx.y * 32, n0 = blockIdx.x * 32;
  int t = threadIdx.x;
  int r = t >> 3, c = (t & 7) * 4;
  float4 v = *(const float4*)(W + (size_t)(k0 + r) * cH + n0 + c);
  tile[r][c] = v.x; tile[r][c + 1] = v.y; tile[r][c + 2] = v.z; tile[r][c + 3] = v.w;
  __syncthreads();
  ushort4 o; u16* op = (u16*)&o;
  #pragma unroll
  for (int j = 0; j < 4; j++) op[j] = f2u(tile[c + j][r]);
  *(ushort4*)(out + (size_t)(n0 + r) * cH + k0 + c) = o;
}

// ---------------- MFMA GEMM: C[M,1024] = A(bf16)[M,1024] @ W, Wt=[n][k] bf16 ----------------
constexpr int GBM = 128, GBN = 128, GLD = 40, TLD = 136;

__global__ __launch_bounds__(256) void mgemm(
    const u16* __restrict__ A, const u16* __restrict__ Wt,
    int a_rpb, int a_base, int a_stride,
    int c_rpb, int mode,
    u16* __restrict__ Cb,
    const float* __restrict__ hidden, const float* __restrict__ cachefull,
    const float* __restrict__ gate, const float* __restrict__ lsc,
    float* __restrict__ outp)
{
  __shared__ __align__(16) u16 smem[128 * TLD];
  u16* As = smem;              // [128][GLD]
  u16* Bs = smem + 128 * GLD;  // [128][GLD]

  int t = threadIdx.x;
  int m0 = blockIdx.y * GBM, n0 = blockIdx.x * GBN;
  int wave = t >> 6, lane = t & 63, l15 = lane & 15, quad = lane >> 4;
  int wm = (wave >> 1) * 64, wn = (wave & 1) * 64;

  int sr = t >> 2, sk = (t & 3) * 8;
  int rg0 = m0 + sr, rg1 = rg0 + 64;
  int ab0 = rg0 / a_rpb, ab1 = rg1 / a_rpb;
  const u16* arow0 = A + (size_t)(ab0 * a_stride + a_base + (rg0 - ab0 * a_rpb)) * cH + sk;
  const u16* arow1 = A + (size_t)(ab1 * a_stride + a_base + (rg1 - ab1 * a_rpb)) * cH + sk;
  const u16* wrow0 = Wt + (size_t)(n0 + sr) * cH + sk;
  const u16* wrow1 = Wt + (size_t)(n0 + sr + 64) * cH + sk;

  f32x4 acc[4][4] = {};

  for (int k0 = 0; k0 < cH; k0 += 32) {
    uint4 a0 = *(const uint4*)(arow0 + k0);
    uint4 a1 = *(const uint4*)(arow1 + k0);
    uint4 b0 = *(const uint4*)(wrow0 + k0);
    uint4 b1 = *(const uint4*)(wrow1 + k0);
    __syncthreads();
    *(uint4*)&As[sr * GLD + sk] = a0;
    *(uint4*)&As[(sr + 64) * GLD + sk] = a1;
    *(uint4*)&Bs[sr * GLD + sk] = b0;
    *(uint4*)&Bs[(sr + 64) * GLD + sk] = b1;
    __syncthreads();
    s16x8 af[4], bf[4];
    #pragma unroll
    for (int mt = 0; mt < 4; mt++)
      af[mt] = *(const s16x8*)&As[(wm + mt * 16 + l15) * GLD + quad * 8];
    #pragma unroll
    for (int nt = 0; nt < 4; nt++)
      bf[nt] = *(const s16x8*)&Bs[(wn + nt * 16 + l15) * GLD + quad * 8];
    #pragma unroll
    for (int mt = 0; mt < 4; mt++)
      #pragma unroll
      for (int nt = 0; nt < 4; nt++)
        acc[mt][nt] = __builtin_amdgcn_mfma_f32_16x16x32_bf16(af[mt], bf[nt], acc[mt][nt], 0, 0, 0);
  }

  if (mode == 1) {
    #pragma unroll
    for (int mt = 0; mt < 4; mt++)
      #pragma unroll
      for (int i = 0; i < 4; i++) {
        int rg = m0 + wm + mt * 16 + quad * 4 + i;
        int bo = rg / c_rpb, lo = rg - bo * c_rpb;
        #pragma unroll
        for (int nt = 0; nt < 4; nt++) {
          int n = n0 + wn + nt * 16 + l15;
          int h = n >> 6, d = n & 63;
          Cb[(((size_t)(bo * cNH + h) * c_rpb + lo) * cHD) + d] = f2u(acc[mt][nt][i]);
        }
      }
  } else if (mode == 3) {
    u16* t2 = smem;
    __syncthreads();
    #pragma unroll
    for (int mt = 0; mt < 4; mt++)
      #pragma unroll
      for (int nt = 0; nt < 4; nt++) {
        ushort4 o; u16* op = (u16*)&o;
        #pragma unroll
        for (int i = 0; i < 4; i++) op[i] = f2u(acc[mt][nt][i]);
        *(ushort4*)&t2[(size_t)(wn + nt * 16 + l15) * TLD + wm + mt * 16 + quad * 4] = o;
      }
    __syncthreads();
    int n_l = t >> 1, mh = (t & 1) * 64;
    int bo = m0 / c_rpb;
    int lo = m0 - bo * c_rpb + mh;
    int n = n0 + n_l, h = n >> 6, d = n & 63;
    u16* dst = Cb + ((size_t)(bo * cNH + h) * cHD + d) * (size_t)c_rpb + lo;
    #pragma unroll
    for (int j = 0; j < 8; j++)
      *(uint4*)(dst + j * 8) = *(const uint4*)&t2[(size_t)n_l * TLD + mh + j * 8];
  } else {
    float gv[4], lv[4];
    #pragma unroll
    for (int nt = 0; nt < 4; nt++) {
      int n = n0 + wn + nt * 16 + l15;
      gv[nt] = 1.f / (1.f + __expf(-gate[n]));
      lv[nt] = lsc[n];
    }
    #pragma unroll
    for (int mt = 0; mt < 4; mt++)
      #pragma unroll
      for (int i = 0; i < 4; i++) {
        int rg = m0 + wm + mt * 16 + quad * 4 + i;
        size_t rbase = (size_t)rg * cH;
        #pragma unroll
        for (int nt = 0; nt < 4; nt++) {
          int n = n0 + wn + nt * 16 + l15;
          float hid = hidden[rbase + n];
          float cr = cachefull[(size_t)3 * cB * cS * cH + rbase + n];
          outp[rbase + n] = hid + lv[nt] * (gv[nt] * acc[mt][nt][i] + (1.f - gv[nt]) * cr);
        }
      }
  }
}

// ---------------- RoPE in-place on head-major bf16 [b*h][rows][64] ----------------
__global__ __launch_bounds__(256) void rope_b16(u16* __restrict__ X, int rows) {
  size_t idx = (size_t)blockIdx.x * 256 + threadIdx.x;
  int d = (int)(idx & 31);
  size_t rest = idx >> 5;
  int row = (int)(rest % rows);
  size_t bh = rest / rows;
  u16* xp = X + (bh * rows + row) * cHD;
  int pos = row & (cS - 1);
  float freq = exp2f(-(float)d * (13.287712379549449f / 32.f)); // 10000^(-d/32)
  float ang = (float)pos * freq;
  float sn, cs;
  sincosf(ang, &sn, &cs);
  float x1 = u2f(xp[d]), x2 = u2f(xp[d + 32]);
  xp[d] = f2u(x1 * cs - x2 * sn);
  xp[d + 32] = f2u(x1 * sn + x2 * cs);
}

// ---------------- MFMA flash attention, split-K over key quarters ----------------
// blockIdx.z = split*cB + b.  Outputs unnormalized partial O (f32) + (m,l) per row.
constexpr int ACK = 64;
constexpr int PLD = 72;
constexpr int KSPLIT = 4;
constexpr int KS = cL / KSPLIT;      // 1280 keys per split
constexpr int NRB = cB * cNH * cS;   // rows per split (32768)

__global__ __launch_bounds__(256, 8) void attn_mfma(
    const u16* __restrict__ Q, const u16* __restrict__ K, const u16* __restrict__ Vt,
    float* __restrict__ o0, float* __restrict__ o1,
    float* __restrict__ o2, float* __restrict__ o3,
    float* __restrict__ mlbuf)
{
  __shared__ u16 pbuf[4][16 * PLD];

  int t = threadIdx.x;
  int wave = t >> 6, lane = t & 63;
  int l15 = lane & 15, quad = lane >> 4;
  int qt = blockIdx.x, h = blockIdx.y;
  int bz = blockIdx.z;
  int b = bz & (cB - 1), split = bz >> 1;
  int q0 = qt * 64 + wave * 16;
  int kbase = split * KS;

  const u16* qp = Q + ((size_t)(b * cNH + h) * cS + q0) * cHD;
  const u16* kp = K + ((size_t)(b * cNH + h) * cL + kbase) * cHD;
  const u16* vp = Vt + (size_t)(b * cNH + h) * cHD * cL + kbase;
  u16* pw = pbuf[wave];

  s16x8 qf0 = ld_frag(qp + (size_t)l15 * cHD + quad * 8);
  s16x8 qf1 = ld_frag(qp + (size_t)l15 * cHD + 32 + quad * 8);

  f32x4 oacc[4] = {};
  float mrow[4], lrow[4];
  #pragma unroll
  for (int i = 0; i < 4; i++) { mrow[i] = -1e30f; lrow[i] = 0.f; }

  constexpr float SCL = 0.125f * 1.4426950408889634f;

  for (int kt = 0; kt < KS / ACK; kt++) {
    // ---- hoisted V loads (latency covered by scores+softmax below) ----
    uint4 vreg[8];
    #pragma unroll
    for (int dt = 0; dt < 4; dt++) {
      const u16* vr = vp + (size_t)(dt * 16 + l15) * cL + kt * ACK;
      vreg[2 * dt]     = *(const uint4*)(vr + quad * 8);
      vreg[2 * dt + 1] = *(const uint4*)(vr + 32 + quad * 8);
    }
    const u16* kc = kp + (size_t)kt * ACK * cHD;
    f32x4 sc[4];
    #pragma unroll
    for (int nt = 0; nt < 4; nt++) {
      s16x8 kf0 = ld_frag(kc + (size_t)(nt * 16 + l15) * cHD + quad * 8);
      s16x8 kf1 = ld_frag(kc + (size_t)(nt * 16 + l15) * cHD + 32 + quad * 8);
      f32x4 a = {};
      a = __builtin_amdgcn_mfma_f32_16x16x32_bf16(qf0, kf0, a, 0, 0, 0);
      a = __builtin_amdgcn_mfma_f32_16x16x32_bf16(qf1, kf1, a, 0, 0, 0);
      sc[nt] = a * SCL;
    }
    float mx[4];
    #pragma unroll
    for (int i = 0; i < 4; i++)
      mx[i] = fmaxf(fmaxf(sc[0][i], sc[1][i]), fmaxf(sc[2][i], sc[3][i]));
    #pragma unroll
    for (int off = 1; off < 16; off <<= 1)
      #pragma unroll
      for (int i = 0; i < 4; i++) mx[i] = fmaxf(mx[i], __shfl_xor(mx[i], off));
    float alpha[4];
    #pragma unroll
    for (int i = 0; i < 4; i++) {
      float mn = fmaxf(mrow[i], mx[i]);
      alpha[i] = exp2f(mrow[i] - mn);
      mrow[i] = mn;
    }
    float ps[4] = {};
    #pragma unroll
    for (int nt = 0; nt < 4; nt++)
      #pragma unroll
      for (int i = 0; i < 4; i++) {
        float p = exp2f(sc[nt][i] - mrow[i]);
        ps[i] += p;
        pw[(quad * 4 + i) * PLD + nt * 16 + l15] = f2u(p);
      }
    #pragma unroll
    for (int off = 1; off < 16; off <<= 1)
      #pragma unroll
      for (int i = 0; i < 4; i++) ps[i] += __shfl_xor(ps[i], off);
    #pragma unroll
    for (int i = 0; i < 4; i++) lrow[i] = lrow[i] * alpha[i] + ps[i];
    #pragma unroll
    for (int dt = 0; dt < 4; dt++)
      #pragma unroll
      for (int i = 0; i < 4; i++) oacc[dt][i] *= alpha[i];
    s16x8 pf0 = *(const s16x8*)&pw[l15 * PLD + quad * 8];
    s16x8 pf1 = *(const s16x8*)&pw[l15 * PLD + 32 + quad * 8];
    #pragma unroll
    for (int dt = 0; dt < 4; dt++) {
      oacc[dt] = __builtin_amdgcn_mfma_f32_16x16x32_bf16(pf0, u4_frag(vreg[2 * dt]), oacc[dt], 0, 0, 0);
      oacc[dt] = __builtin_amdgcn_mfma_f32_16x16x32_bf16(pf1, u4_frag(vreg[2 * dt + 1]), oacc[dt], 0, 0, 0);
    }
  }
  // ---- epilogue: unnormalized partial O + (m,l) ----
  float* ob = (split == 0) ? o0 : (split == 1) ? o1 : (split == 2) ? o2 : o3;
  #pragma unroll
  for (int i = 0; i < 4; i++) {
    int q = q0 + quad * 4 + i;
    size_t Rl = (size_t)(b * cNH + h) * cS + q;
    float* orow = ob + Rl * cHD;
    #pragma unroll
    for (int dt = 0; dt < 4; dt++)
      orow[dt * 16 + l15] = oacc[dt][i];
    if (l15 == 0) {
      mlbuf[((size_t)split * NRB + Rl) * 2] = mrow[i];
      mlbuf[((size_t)split * NRB + Rl) * 2 + 1] = lrow[i];
    }
  }
}

// ---------------- split-K merge: combine four softmax partials -> bf16 ctx ----------------
__global__ __launch_bounds__(256) void attn_merge(
    const float* __restrict__ o0, const float* __restrict__ o1,
    const float* __restrict__ o2, const float* __restrict__ o3,
    const float* __restrict__ mlbuf, u16* __restrict__ ctx)
{
  int t = threadIdx.x;
  int R = blockIdx.x * 4 + (t >> 6);   // (b*cNH+h)*cS + q
  int d = t & 63;
  float ms[KSPLIT], ls[KSPLIT];
  float m = -1e30f;
  #pragma unroll
  for (int s = 0; s < KSPLIT; s++) {
    ms[s] = mlbuf[((size_t)s * NRB + R) * 2];
    ls[s] = mlbuf[((size_t)s * NRB + R) * 2 + 1];
    m = fmaxf(m, ms[s]);
  }
  const float* ops[KSPLIT] = {o0, o1, o2, o3};
  float num = 0.f, den = 0.f;
  #pragma unroll
  for (int s = 0; s < KSPLIT; s++) {
    float a = exp2f(ms[s] - m);
    num += ops[s][(size_t)R * cHD + d] * a;
    den += ls[s] * a;
  }
  float val = num / den;
  int q = R & (cS - 1), h = (R >> 10) & 15, b = R >> 14;
  ctx[((size_t)b * cS + q) * cH + h * cHD + d] = f2u(val);
}

extern "C" void kernel_launch(void* const* d_in, const int* in_sizes, int n_in,
                              void* d_out, int out_size, void* d_ws, size_t ws_size,
                              hipStream_t stream)
{
  const float* hidden = (const float*)d_in[0];
  const float* cache  = (const float*)d_in[1];
  const float* ln_s   = (const float*)d_in[2];
  const float* ln_b   = (const float*)d_in[3];
  const float* Wq     = (const float*)d_in[4];
  const float* Wk     = (const float*)d_in[5];
  const float* Wv     = (const float*)d_in[6];
  const float* Wo     = (const float*)d_in[7];
  const float* gate   = (const float*)d_in[8];
  const float* lsc    = (const float*)d_in[9];
  float* outp = (float*)d_out;

  // ws: kvin 20.97M | vt 20.97M | opart(splits 0,1) 16.78M  (~58.7 MB)
  u16* kvin = (u16*)d_ws;
  u16* vt   = kvin + (size_t)cB * cL * cH;
  float* opart = (float*)(vt + (size_t)cB * cL * cH);
  float* o0 = opart;
  float* o1 = opart + (size_t)cB * cNH * cS * cHD;          // +8.39MB
  // aliases into kvin (dead rows by the time these are written):
  u16* qb  = kvin;                                // [0, 4.19M) written by Q GEMM (last kvin reader)
  u16* ctx = kvin + (size_t)2 * 1024 * 1024;      // [4.19M, 8.39M) written by attn_merge
  float* o2 = (float*)(kvin + (size_t)4 * 1024 * 1024);   // bytes [8.39M, 16.78M)
  float* mlbuf = (float*)(kvin + (size_t)8 * 1024 * 1024);// bytes [16.78M, 17.83M), 4 splits
  // split-3 opart parked in d_out output region [0, 8.39M) — written by attn,
  // read by merge, then overwritten by the step-7 GEMM epilogue:
  float* o3 = outp;
  // scratch parked in d_out (overwritten by memcpy/final-LN at the end):
  u16* kb = (u16*)(outp + (size_t)cB * cS * cH);
  u16* Wt = (u16*)(outp + (size_t)(1 + 3) * cB * cS * cH);
  u16* Wt_q = Wt;
  u16* Wt_k = Wt + (size_t)cH * cH;
  u16* Wt_v = Wt + (size_t)2 * cH * cH;
  u16* Wt_o = Wt + (size_t)3 * cH * cH;

  // 1) weight transpose+convert
  wtrans<<<dim3(32, 32, 4), 256, 0, stream>>>(Wq, Wk, Wv, Wo, Wt);
  // 2) cache -> kvin head rows (bf16, permuted)
  cache2kv<<<cB * cW * cS, 256, 0, stream>>>(cache, kvin);
  // 3) pre-norm -> kvin tail rows (bf16)
  ln_bf16<<<cB * cS, 256, 0, stream>>>(hidden, kvin, ln_s, ln_b);

  // 4) K/V/Q projections (MFMA)
  mgemm<<<dim3(8, (cB * cL) / GBM), 256, 0, stream>>>(
      kvin, Wt_k, cL, 0, cL, cL, 1, kb, nullptr, nullptr, nullptr, nullptr, nullptr);
  mgemm<<<dim3(8, (cB * cL) / GBM), 256, 0, stream>>>(
      kvin, Wt_v, cL, 0, cL, cL, 3, vt, nullptr, nullptr, nullptr, nullptr, nullptr);
  mgemm<<<dim3(8, (cB * cS) / GBM), 256, 0, stream>>>(
      kvin, Wt_q, cS, cW * cS, cL, cS, 1, qb, nullptr, nullptr, nullptr, nullptr, nullptr);

  // 5) RoPE on Q and K
  rope_b16<<<(cB * cNH * cS * 32) / 256, 256, 0, stream>>>(qb, cS);
  rope_b16<<<(cB * cNH * cL * 32) / 256, 256, 0, stream>>>(kb, cL);

  // 6) 4-way split-K MFMA flash attention -> partials, then merge -> ctx (bf16)
  attn_mfma<<<dim3(cS / 64, cNH, cB * KSPLIT), 256, 0, stream>>>(
      qb, kb, vt, o0, o1, o2, o3, mlbuf);
  attn_merge<<<(cB * cNH * cS) / 4, 256, 0, stream>>>(o0, o1, o2, o3, mlbuf, ctx);

  // 7) ctx @ Wo with fused gated residual -> output f32
  mgemm<<<dim3(8, (cB * cS) / GBM), 256, 0, stream>>>(
      ctx, Wt_o, cB * cS, 0, cB * cS, cB * cS, 2, nullptr,
      hidden, cache, gate, lsc, outp);

  // 8) new_cache[0:3] = cache[1:4]
  hipMemcpyAsync(outp + (size_t)cB * cS * cH, cache + (size_t)cB * cS * cH,
                 (size_t)(cW - 1) * cB * cS * cH * sizeof(float),
                 hipMemcpyDeviceToDevice, stream);
  // 9) final layernorm -> new_cache slot 3
  ln_f32<<<cB * cS, 256, 0, stream>>>(outp, outp + (size_t)cW * cB * cS * cH, ln_s, ln_b);
}

// Round 2
// 511.965 us; speedup vs baseline: 1.4999x; 1.4999x over previous
//
#include <hip/hip_runtime.h>
#include <math.h>

typedef unsigned short u16;

constexpr int cB = 2;
constexpr int cS = 1024;
constexpr int cH = 1024;
constexpr int cNH = 16;
constexpr int cHD = 64;
constexpr int cW = 4;
constexpr int cL = (cW + 1) * cS; // 5120
constexpr float cEPS = 1e-5f;

typedef short s16x8 __attribute__((ext_vector_type(8)));   // 8 bf16 (4 VGPRs)
typedef float f32x4 __attribute__((ext_vector_type(4)));   // MFMA C/D

__device__ __forceinline__ float u2f(u16 u) {
  union { unsigned int i; float f; } x; x.i = ((unsigned int)u) << 16; return x.f;
}
__device__ __forceinline__ u16 f2u(float f) {
  union { float f; unsigned int i; } x; x.f = f;
  unsigned int i = x.i;
  i += 0x7fffu + ((i >> 16) & 1u); // RNE
  return (u16)(i >> 16);
}
__device__ __forceinline__ s16x8 ld_frag(const u16* p) {
  uint4 v = *(const uint4*)p;
  union { uint4 u; s16x8 s; } c; c.u = v; return c.s;
}
__device__ __forceinline__ s16x8 u4_frag(uint4 v) {
  union { uint4 u; s16x8 s; } c; c.u = v; return c.s;
}
// async 16B global -> LDS (dest = wave-uniform base + lane*16)
__device__ __forceinline__ void gl_lds16(const u16* g, u16* l) {
  __builtin_amdgcn_global_load_lds(
      (const __attribute__((address_space(1))) unsigned int*)g,
      (__attribute__((address_space(3))) unsigned int*)l, 16, 0, 0);
}

// ---------------- LayerNorm f32 -> f32 (final LN) ----------------
__global__ __launch_bounds__(256) void ln_f32(
    const float* __restrict__ src, float* __restrict__ dst,
    const float* __restrict__ scale, const float* __restrict__ bias)
{
  int r = blockIdx.x;
  int t = threadIdx.x;
  const float* sp = src + (size_t)r * cH;
  float4 x = ((const float4*)sp)[t];
  float s1 = x.x + x.y + x.z + x.w;
  float s2 = x.x * x.x + x.y * x.y + x.z * x.z + x.w * x.w;
  #pragma unroll
  for (int off = 32; off > 0; off >>= 1) {
    s1 += __shfl_down(s1, off);
    s2 += __shfl_down(s2, off);
  }
  __shared__ float w1[4], w2[4];
  __shared__ float stat[2];
  int wid = t >> 6, lid = t & 63;
  if (lid == 0) { w1[wid] = s1; w2[wid] = s2; }
  __syncthreads();
  if (t == 0) {
    float a = w1[0] + w1[1] + w1[2] + w1[3];
    float b = w2[0] + w2[1] + w2[2] + w2[3];
    float mu = a * (1.f / cH);
    float var = b * (1.f / cH) - mu * mu;
    if (var < 0.f) var = 0.f;
    stat[0] = mu; stat[1] = rsqrtf(var + cEPS);
  }
  __syncthreads();
  float mu = stat[0], rs = stat[1];
  int h0 = t * 4;
  float4 sc = *(const float4*)(scale + h0);
  float4 bi = *(const float4*)(bias + h0);
  float4 o;
  o.x = (x.x - mu) * rs * sc.x + bi.x;
  o.y = (x.y - mu) * rs * sc.y + bi.y;
  o.z = (x.z - mu) * rs * sc.z + bi.z;
  o.w = (x.w - mu) * rs * sc.w + bi.w;
  *(float4*)(dst + (size_t)r * cH + h0) = o;
}

// ---------------- LayerNorm f32 -> bf16 into kvin tail ----------------
__global__ __launch_bounds__(256) void ln_bf16(
    const float* __restrict__ src, u16* __restrict__ kvin,
    const float* __restrict__ scale, const float* __restrict__ bias)
{
  int r = blockIdx.x;            // 0..cB*cS-1
  int t = threadIdx.x;
  const float* sp = src + (size_t)r * cH;
  float4 x = ((const float4*)sp)[t];
  float s1 = x.x + x.y + x.z + x.w;
  float s2 = x.x * x.x + x.y * x.y + x.z * x.z + x.w * x.w;
  #pragma unroll
  for (int off = 32; off > 0; off >>= 1) {
    s1 += __shfl_down(s1, off);
    s2 += __shfl_down(s2, off);
  }
  __shared__ float w1[4], w2[4];
  __shared__ float stat[2];
  int wid = t >> 6, lid = t & 63;
  if (lid == 0) { w1[wid] = s1; w2[wid] = s2; }
  __syncthreads();
  if (t == 0) {
    float a = w1[0] + w1[1] + w1[2] + w1[3];
    float b = w2[0] + w2[1] + w2[2] + w2[3];
    float mu = a * (1.f / cH);
    float var = b * (1.f / cH) - mu * mu;
    if (var < 0.f) var = 0.f;
    stat[0] = mu; stat[1] = rsqrtf(var + cEPS);
  }
  __syncthreads();
  float mu = stat[0], rs = stat[1];
  int h0 = t * 4;
  float4 sc = *(const float4*)(scale + h0);
  float4 bi = *(const float4*)(bias + h0);
  int b = r >> 10, s = r & (cS - 1);
  u16* dp = kvin + ((size_t)(b * cL + cW * cS + s)) * cH + h0;
  ushort4 o; u16* op = (u16*)&o;
  op[0] = f2u((x.x - mu) * rs * sc.x + bi.x);
  op[1] = f2u((x.y - mu) * rs * sc.y + bi.y);
  op[2] = f2u((x.z - mu) * rs * sc.z + bi.z);
  op[3] = f2u((x.w - mu) * rs * sc.w + bi.w);
  *(ushort4*)dp = o;
}

// -------- cache f32 [W,B,S,H] -> kvin bf16 [B, w*S+s, H] --------
__global__ __launch_bounds__(256) void cache2kv(const float* __restrict__ cache,
                                                u16* __restrict__ kvin) {
  int blk = blockIdx.x;          // cB*cW*cS = 8192
  int b = blk >> 12, w = (blk >> 10) & 3, s = blk & 1023;
  const float* src = cache + ((size_t)((w * cB + b) * cS + s)) * cH;
  u16* dst = kvin + ((size_t)(b * cL + w * cS + s)) * cH;
  int t = threadIdx.x;
  float4 v = *(const float4*)(src + t * 4);
  ushort4 o; u16* op = (u16*)&o;
  op[0] = f2u(v.x); op[1] = f2u(v.y); op[2] = f2u(v.z); op[3] = f2u(v.w);
  *(ushort4*)(dst + t * 4) = o;
}

// -------- weight transpose: W f32 [k][n] -> Wt bf16 [n][k], 4 matrices --------
__global__ __launch_bounds__(256) void wtrans(
    const float* __restrict__ W0, const float* __restrict__ W1,
    const float* __restrict__ W2, const float* __restrict__ W3,
    u16* __restrict__ Wt)
{
  __shared__ float tile[32][33];
  int mat = blockIdx.z;
  const float* W = (mat == 0) ? W0 : (mat == 1) ? W1 : (mat == 2) ? W2 : W3;
  u16* out = Wt + (size_t)mat * cH * cH;
  int k0 = blockIdx.y * 32, n0 = blockIdx.x * 32;
  int t = threadIdx.x;
  int r = t >> 3, c = (t & 7) * 4;
  float4 v = *(const float4*)(W + (size_t)(k0 + r) * cH + n0 + c);
  tile[r][c] = v.x; tile[r][c + 1] = v.y; tile[r][c + 2] = v.z; tile[r][c + 3] = v.w;
  __syncthreads();
  ushort4 o; u16* op = (u16*)&o;
  #pragma unroll
  for (int j = 0; j < 4; j++) op[j] = f2u(tile[c + j][r]);
  *(ushort4*)(out + (size_t)(n0 + r) * cH + k0 + c) = o;
}

// ---------------- MFMA GEMM: C[M,1024] = A(bf16)[M,1024] @ W, Wt=[n][k] bf16 ----------------
constexpr int GBM = 128, GBN = 128, GLD = 40, TLD = 136;

__global__ __launch_bounds__(256) void mgemm(
    const u16* __restrict__ A, const u16* __restrict__ Wt,
    int a_rpb, int a_base, int a_stride,
    int c_rpb, int mode,
    u16* __restrict__ Cb,
    const float* __restrict__ hidden, const float* __restrict__ cachefull,
    const float* __restrict__ gate, const float* __restrict__ lsc,
    float* __restrict__ outp)
{
  __shared__ __align__(16) u16 smem[128 * TLD];
  u16* As = smem;              // [128][GLD]
  u16* Bs = smem + 128 * GLD;  // [128][GLD]

  int t = threadIdx.x;
  int m0 = blockIdx.y * GBM, n0 = blockIdx.x * GBN;
  int wave = t >> 6, lane = t & 63, l15 = lane & 15, quad = lane >> 4;
  int wm = (wave >> 1) * 64, wn = (wave & 1) * 64;

  int sr = t >> 2, sk = (t & 3) * 8;
  int rg0 = m0 + sr, rg1 = rg0 + 64;
  int ab0 = rg0 / a_rpb, ab1 = rg1 / a_rpb;
  const u16* arow0 = A + (size_t)(ab0 * a_stride + a_base + (rg0 - ab0 * a_rpb)) * cH + sk;
  const u16* arow1 = A + (size_t)(ab1 * a_stride + a_base + (rg1 - ab1 * a_rpb)) * cH + sk;
  const u16* wrow0 = Wt + (size_t)(n0 + sr) * cH + sk;
  const u16* wrow1 = Wt + (size_t)(n0 + sr + 64) * cH + sk;

  f32x4 acc[4][4] = {};

  for (int k0 = 0; k0 < cH; k0 += 32) {
    uint4 a0 = *(const uint4*)(arow0 + k0);
    uint4 a1 = *(const uint4*)(arow1 + k0);
    uint4 b0 = *(const uint4*)(wrow0 + k0);
    uint4 b1 = *(const uint4*)(wrow1 + k0);
    __syncthreads();
    *(uint4*)&As[sr * GLD + sk] = a0;
    *(uint4*)&As[(sr + 64) * GLD + sk] = a1;
    *(uint4*)&Bs[sr * GLD + sk] = b0;
    *(uint4*)&Bs[(sr + 64) * GLD + sk] = b1;
    __syncthreads();
    s16x8 af[4], bf[4];
    #pragma unroll
    for (int mt = 0; mt < 4; mt++)
      af[mt] = *(const s16x8*)&As[(wm + mt * 16 + l15) * GLD + quad * 8];
    #pragma unroll
    for (int nt = 0; nt < 4; nt++)
      bf[nt] = *(const s16x8*)&Bs[(wn + nt * 16 + l15) * GLD + quad * 8];
    #pragma unroll
    for (int mt = 0; mt < 4; mt++)
      #pragma unroll
      for (int nt = 0; nt < 4; nt++)
        acc[mt][nt] = __builtin_amdgcn_mfma_f32_16x16x32_bf16(af[mt], bf[nt], acc[mt][nt], 0, 0, 0);
  }

  if (mode == 1) {
    #pragma unroll
    for (int mt = 0; mt < 4; mt++)
      #pragma unroll
      for (int i = 0; i < 4; i++) {
        int rg = m0 + wm + mt * 16 + quad * 4 + i;
        int bo = rg / c_rpb, lo = rg - bo * c_rpb;
        #pragma unroll
        for (int nt = 0; nt < 4; nt++) {
          int n = n0 + wn + nt * 16 + l15;
          int h = n >> 6, d = n & 63;
          Cb[(((size_t)(bo * cNH + h) * c_rpb + lo) * cHD) + d] = f2u(acc[mt][nt][i]);
        }
      }
  } else if (mode == 3) {
    u16* t2 = smem;
    __syncthreads();
    #pragma unroll
    for (int mt = 0; mt < 4; mt++)
      #pragma unroll
      for (int nt = 0; nt < 4; nt++) {
        ushort4 o; u16* op = (u16*)&o;
        #pragma unroll
        for (int i = 0; i < 4; i++) op[i] = f2u(acc[mt][nt][i]);
        *(ushort4*)&t2[(size_t)(wn + nt * 16 + l15) * TLD + wm + mt * 16 + quad * 4] = o;
      }
    __syncthreads();
    int n_l = t >> 1, mh = (t & 1) * 64;
    int bo = m0 / c_rpb;
    int lo = m0 - bo * c_rpb + mh;
    int n = n0 + n_l, h = n >> 6, d = n & 63;
    u16* dst = Cb + ((size_t)(bo * cNH + h) * cHD + d) * (size_t)c_rpb + lo;
    #pragma unroll
    for (int j = 0; j < 8; j++)
      *(uint4*)(dst + j * 8) = *(const uint4*)&t2[(size_t)n_l * TLD + mh + j * 8];
  } else {
    float gv[4], lv[4];
    #pragma unroll
    for (int nt = 0; nt < 4; nt++) {
      int n = n0 + wn + nt * 16 + l15;
      gv[nt] = 1.f / (1.f + __expf(-gate[n]));
      lv[nt] = lsc[n];
    }
    #pragma unroll
    for (int mt = 0; mt < 4; mt++)
      #pragma unroll
      for (int i = 0; i < 4; i++) {
        int rg = m0 + wm + mt * 16 + quad * 4 + i;
        size_t rbase = (size_t)rg * cH;
        #pragma unroll
        for (int nt = 0; nt < 4; nt++) {
          int n = n0 + wn + nt * 16 + l15;
          float hid = hidden[rbase + n];
          float cr = cachefull[(size_t)3 * cB * cS * cH + rbase + n];
          outp[rbase + n] = hid + lv[nt] * (gv[nt] * acc[mt][nt][i] + (1.f - gv[nt]) * cr);
        }
      }
  }
}

// ---------------- RoPE in-place on head-major bf16 [b*h][rows][64] ----------------
__global__ __launch_bounds__(256) void rope_b16(u16* __restrict__ X, int rows) {
  size_t idx = (size_t)blockIdx.x * 256 + threadIdx.x;
  int d = (int)(idx & 31);
  size_t rest = idx >> 5;
  int row = (int)(rest % rows);
  size_t bh = rest / rows;
  u16* xp = X + (bh * rows + row) * cHD;
  int pos = row & (cS - 1);
  float freq = exp2f(-(float)d * (13.287712379549449f / 32.f)); // 10000^(-d/32)
  float ang = (float)pos * freq;
  float sn, cs;
  sincosf(ang, &sn, &cs);
  float x1 = u2f(xp[d]), x2 = u2f(xp[d + 32]);
  xp[d] = f2u(x1 * cs - x2 * sn);
  xp[d + 32] = f2u(x1 * sn + x2 * cs);
}

// ---------------- MFMA flash attention, split-K over key halves ----------------
// K tiles staged in LDS (double-buffered, XOR-swizzled, global_load_lds,
// counted vmcnt, raw barriers).  All 4 waves of a block share the K tile.
constexpr int ACK = 64;
constexpr int PLD = 72;
constexpr int KSPLIT = 2;
constexpr int KS = cL / KSPLIT;      // 2560 keys per split
constexpr int NIT = KS / ACK;        // 40 tiles

__global__ __launch_bounds__(256, 4) void attn_mfma(
    const u16* __restrict__ Q, const u16* __restrict__ K, const u16* __restrict__ Vt,
    float* __restrict__ opart, float* __restrict__ mlbuf)
{
  // 2 x (64 keys x 64 d) bf16 = 2 x 8 KB, XOR-swizzled: phys = log ^ ((row&7)<<4)
  __shared__ __align__(16) u16 kls[2][ACK * cHD];
  __shared__ u16 pbuf[4][16 * PLD];

  int t = threadIdx.x;
  int wave = t >> 6, lane = t & 63;
  int l15 = lane & 15, quad = lane >> 4;
  int qt = blockIdx.x, h = blockIdx.y;
  int bz = blockIdx.z;
  int b = bz >> 1, split = bz & 1;
  int q0 = qt * 64 + wave * 16;
  int kbase = split * KS;

  const u16* qp = Q + ((size_t)(b * cNH + h) * cS + q0) * cHD;
  const char* kp = (const char*)(K + ((size_t)(b * cNH + h) * cL + kbase) * cHD);
  const u16* vp = Vt + (size_t)(b * cNH + h) * cHD * cL + kbase;
  u16* pw = pbuf[wave];

  // staging geometry: thread covers phys bytes P0 and P0+4096 of the 8 KB tile;
  // source is pre-swizzled so swizzled reads see logical layout (involution).
  int P0 = wave * 1024 + lane * 16;
  int P1 = P0 + 4096;
  int s0 = P0 ^ (((P0 >> 7) & 7) << 4);
  int s1 = P1 ^ (((P1 >> 7) & 7) << 4);
  // swizzled fragment column offsets for ds_read_b128 (row&7 == l15&7)
  int fsw0 = (quad * 16) ^ ((l15 & 7) << 4);
  int fsw1 = (64 + quad * 16) ^ ((l15 & 7) << 4);

  s16x8 qf0 = ld_frag(qp + (size_t)l15 * cHD + quad * 8);
  s16x8 qf1 = ld_frag(qp + (size_t)l15 * cHD + 32 + quad * 8);

  // prologue: stage tile 0 into buffer 0
  gl_lds16((const u16*)(kp + s0), (u16*)((char*)&kls[0][0] + wave * 1024));
  gl_lds16((const u16*)(kp + s1), (u16*)((char*)&kls[0][0] + 4096 + wave * 1024));

  f32x4 oacc[4] = {};
  float mrow[4], lrow[4];
  #pragma unroll
  for (int i = 0; i < 4; i++) { mrow[i] = -1e30f; lrow[i] = 0.f; }

  constexpr float SCL = 0.125f * 1.4426950408889634f;

  for (int kt = 0; kt < NIT; kt++) {
    int cur = kt & 1;
    // ---- V loads for this tile (latency covered by QK+softmax below) ----
    uint4 vreg[8];
    #pragma unroll
    for (int dt = 0; dt < 4; dt++) {
      const u16* vr = vp + (size_t)(dt * 16 + l15) * cL + kt * ACK;
      vreg[2 * dt]     = *(const uint4*)(vr + quad * 8);
      vreg[2 * dt + 1] = *(const uint4*)(vr + 32 + quad * 8);
    }
    // ---- barrier A: all waves done reading kls[cur^1] (prev iter) ----
    asm volatile("" ::: "memory");
    __builtin_amdgcn_s_barrier();
    asm volatile("" ::: "memory");
    // ---- stage next tile into kls[cur^1] ----
    int nk = kt + 1; if (nk == NIT) nk = 0;
    const char* kn = kp + (size_t)nk * (ACK * cHD * 2);
    gl_lds16((const u16*)(kn + s0), (u16*)((char*)&kls[cur ^ 1][0] + wave * 1024));
    gl_lds16((const u16*)(kn + s1), (u16*)((char*)&kls[cur ^ 1][0] + 4096 + wave * 1024));
    // ---- wait own stage of tile kt (10 newer ops: 8 V + 2 stage-next) ----
    asm volatile("s_waitcnt vmcnt(10)" ::: "memory");
    __builtin_amdgcn_s_barrier();
    asm volatile("" ::: "memory");
    // ---- QK^T from LDS (swizzled reads, conflict-free) ----
    const char* kc = (const char*)&kls[cur][0];
    f32x4 sc[4];
    #pragma unroll
    for (int nt = 0; nt < 4; nt++) {
      s16x8 kf0 = *(const s16x8*)(kc + (nt * 16 + l15) * 128 + fsw0);
      s16x8 kf1 = *(const s16x8*)(kc + (nt * 16 + l15) * 128 + fsw1);
      f32x4 a = {};
      a = __builtin_amdgcn_mfma_f32_16x16x32_bf16(qf0, kf0, a, 0, 0, 0);
      a = __builtin_amdgcn_mfma_f32_16x16x32_bf16(qf1, kf1, a, 0, 0, 0);
      sc[nt] = a * SCL;
    }
    // ---- online softmax ----
    float mx[4];
    #pragma unroll
    for (int i = 0; i < 4; i++)
      mx[i] = fmaxf(fmaxf(sc[0][i], sc[1][i]), fmaxf(sc[2][i], sc[3][i]));
    #pragma unroll
    for (int off = 1; off < 16; off <<= 1)
      #pragma unroll
      for (int i = 0; i < 4; i++) mx[i] = fmaxf(mx[i], __shfl_xor(mx[i], off));
    float alpha[4];
    #pragma unroll
    for (int i = 0; i < 4; i++) {
      float mn = fmaxf(mrow[i], mx[i]);
      alpha[i] = exp2f(mrow[i] - mn);
      mrow[i] = mn;
    }
    float ps[4] = {};
    #pragma unroll
    for (int nt = 0; nt < 4; nt++)
      #pragma unroll
      for (int i = 0; i < 4; i++) {
        float p = exp2f(sc[nt][i] - mrow[i]);
        ps[i] += p;
        pw[(quad * 4 + i) * PLD + nt * 16 + l15] = f2u(p);
      }
    #pragma unroll
    for (int off = 1; off < 16; off <<= 1)
      #pragma unroll
      for (int i = 0; i < 4; i++) ps[i] += __shfl_xor(ps[i], off);
    #pragma unroll
    for (int i = 0; i < 4; i++) lrow[i] = lrow[i] * alpha[i] + ps[i];
    #pragma unroll
    for (int dt = 0; dt < 4; dt++)
      #pragma unroll
      for (int i = 0; i < 4; i++) oacc[dt][i] *= alpha[i];
    // ---- PV ----
    s16x8 pf0 = *(const s16x8*)&pw[l15 * PLD + quad * 8];
    s16x8 pf1 = *(const s16x8*)&pw[l15 * PLD + 32 + quad * 8];
    #pragma unroll
    for (int dt = 0; dt < 4; dt++) {
      oacc[dt] = __builtin_amdgcn_mfma_f32_16x16x32_bf16(pf0, u4_frag(vreg[2 * dt]), oacc[dt], 0, 0, 0);
      oacc[dt] = __builtin_amdgcn_mfma_f32_16x16x32_bf16(pf1, u4_frag(vreg[2 * dt + 1]), oacc[dt], 0, 0, 0);
    }
  }
  // ---- epilogue: unnormalized partial O + (m,l) ----
  #pragma unroll
  for (int i = 0; i < 4; i++) {
    int q = q0 + quad * 4 + i;
    size_t R = ((size_t)(split * cB + b) * cNH + h) * cS + q;
    float* orow = opart + R * cHD;
    #pragma unroll
    for (int dt = 0; dt < 4; dt++)
      orow[dt * 16 + l15] = oacc[dt][i];
    if (l15 == 0) {
      mlbuf[R * 2] = mrow[i];
      mlbuf[R * 2 + 1] = lrow[i];
    }
  }
}

// ---------------- split-K merge: combine two softmax partials -> bf16 ctx ----------------
__global__ __launch_bounds__(256) void attn_merge(
    const float* __restrict__ opart, const float* __restrict__ mlbuf,
    u16* __restrict__ ctx)
{
  int t = threadIdx.x;
  int R = blockIdx.x * 4 + (t >> 6);   // (b*cNH+h)*cS + q
  int d = t & 63;
  const size_t NR = (size_t)cB * cNH * cS;
  float m1 = mlbuf[(size_t)R * 2],        l1 = mlbuf[(size_t)R * 2 + 1];
  float m2 = mlbuf[(NR + R) * 2],         l2 = mlbuf[(NR + R) * 2 + 1];
  float m = fmaxf(m1, m2);
  float a1 = exp2f(m1 - m), a2 = exp2f(m2 - m);
  float inv = 1.f / (l1 * a1 + l2 * a2);
  float o1 = opart[(size_t)R * cHD + d];
  float o2 = opart[(NR + R) * cHD + d];
  float val = (o1 * a1 + o2 * a2) * inv;
  int q = R & (cS - 1), h = (R >> 10) & 15, b = R >> 14;
  ctx[((size_t)b * cS + q) * cH + h * cHD + d] = f2u(val);
}

extern "C" void kernel_launch(void* const* d_in, const int* in_sizes, int n_in,
                              void* d_out, int out_size, void* d_ws, size_t ws_size,
                              hipStream_t stream)
{
  const float* hidden = (const float*)d_in[0];
  const float* cache  = (const float*)d_in[1];
  const float* ln_s   = (const float*)d_in[2];
  const float* ln_b   = (const float*)d_in[3];
  const float* Wq     = (const float*)d_in[4];
  const float* Wk     = (const float*)d_in[5];
  const float* Wv     = (const float*)d_in[6];
  const float* Wo     = (const float*)d_in[7];
  const float* gate   = (const float*)d_in[8];
  const float* lsc    = (const float*)d_in[9];
  float* outp = (float*)d_out;

  // ws: kvin 20.97M | vt 20.97M | opart 16.78M | ml 0.52M  (~59.3 MB)
  u16* kvin = (u16*)d_ws;
  u16* vt   = kvin + (size_t)cB * cL * cH;
  float* opart = (float*)(vt + (size_t)cB * cL * cH);
  float* mlbuf = opart + (size_t)KSPLIT * cB * cNH * cS * cHD;
  // aliases into kvin (dead rows by the time these are written):
  u16* qb  = kvin;                               // written by Q GEMM (last kvin reader)
  u16* ctx = kvin + (size_t)2 * 1024 * 1024;     // written by attn_merge
  // scratch parked in d_out (overwritten by memcpy/final-LN at the end):
  u16* kb = (u16*)(outp + (size_t)cB * cS * cH);
  u16* Wt = (u16*)(outp + (size_t)(1 + 3) * cB * cS * cH);
  u16* Wt_q = Wt;
  u16* Wt_k = Wt + (size_t)cH * cH;
  u16* Wt_v = Wt + (size_t)2 * cH * cH;
  u16* Wt_o = Wt + (size_t)3 * cH * cH;

  // 1) weight transpose+convert
  wtrans<<<dim3(32, 32, 4), 256, 0, stream>>>(Wq, Wk, Wv, Wo, Wt);
  // 2) cache -> kvin head rows (bf16, permuted)
  cache2kv<<<cB * cW * cS, 256, 0, stream>>>(cache, kvin);
  // 3) pre-norm -> kvin tail rows (bf16)
  ln_bf16<<<cB * cS, 256, 0, stream>>>(hidden, kvin, ln_s, ln_b);

  // 4) K/V/Q projections (MFMA)
  mgemm<<<dim3(8, (cB * cL) / GBM), 256, 0, stream>>>(
      kvin, Wt_k, cL, 0, cL, cL, 1, kb, nullptr, nullptr, nullptr, nullptr, nullptr);
  mgemm<<<dim3(8, (cB * cL) / GBM), 256, 0, stream>>>(
      kvin, Wt_v, cL, 0, cL, cL, 3, vt, nullptr, nullptr, nullptr, nullptr, nullptr);
  mgemm<<<dim3(8, (cB * cS) / GBM), 256, 0, stream>>>(
      kvin, Wt_q, cS, cW * cS, cL, cS, 1, qb, nullptr, nullptr, nullptr, nullptr, nullptr);

  // 5) RoPE on Q and K
  rope_b16<<<(cB * cNH * cS * 32) / 256, 256, 0, stream>>>(qb, cS);
  rope_b16<<<(cB * cNH * cL * 32) / 256, 256, 0, stream>>>(kb, cL);

  // 6) split-K MFMA flash attention -> partials, then merge -> ctx (bf16)
  attn_mfma<<<dim3(cS / 64, cNH, cB * KSPLIT), 256, 0, stream>>>(qb, kb, vt, opart, mlbuf);
  attn_merge<<<(cB * cNH * cS) / 4, 256, 0, stream>>>(opart, mlbuf, ctx);

  // 7) ctx @ Wo with fused gated residual -> output f32
  mgemm<<<dim3(8, (cB * cS) / GBM), 256, 0, stream>>>(
      ctx, Wt_o, cB * cS, 0, cB * cS, cB * cS, 2, nullptr,
      hidden, cache, gate, lsc, outp);

  // 8) new_cache[0:3] = cache[1:4]
  hipMemcpyAsync(outp + (size_t)cB * cS * cH, cache + (size_t)cB * cS * cH,
                 (size_t)(cW - 1) * cB * cS * cH * sizeof(float),
                 hipMemcpyDeviceToDevice, stream);
  // 9) final layernorm -> new_cache slot 3
  ln_f32<<<cB * cS, 256, 0, stream>>>(outp, outp + (size_t)cW * cB * cS * cH, ln_s, ln_b);
}

// Round 3
// 510.677 us; speedup vs baseline: 1.5036x; 1.0025x over previous
//
#include <hip/hip_runtime.h>
#include <math.h>

typedef unsigned short u16;

constexpr int cB = 2;
constexpr int cS = 1024;
constexpr int cH = 1024;
constexpr int cNH = 16;
constexpr int cHD = 64;
constexpr int cW = 4;
constexpr int cL = (cW + 1) * cS; // 5120
constexpr float cEPS = 1e-5f;

typedef short s16x8 __attribute__((ext_vector_type(8)));   // 8 bf16 (4 VGPRs)
typedef float f32x4 __attribute__((ext_vector_type(4)));   // MFMA C/D

__device__ __forceinline__ float u2f(u16 u) {
  union { unsigned int i; float f; } x; x.i = ((unsigned int)u) << 16; return x.f;
}
__device__ __forceinline__ u16 f2u(float f) {
  union { float f; unsigned int i; } x; x.f = f;
  unsigned int i = x.i;
  i += 0x7fffu + ((i >> 16) & 1u); // RNE
  return (u16)(i >> 16);
}
__device__ __forceinline__ s16x8 ld_frag(const u16* p) {
  uint4 v = *(const uint4*)p;
  union { uint4 u; s16x8 s; } c; c.u = v; return c.s;
}
__device__ __forceinline__ s16x8 u4_frag(uint4 v) {
  union { uint4 u; s16x8 s; } c; c.u = v; return c.s;
}
// async 16B global -> LDS (dest = wave-uniform base + lane*16)
__device__ __forceinline__ void gl_lds16(const u16* g, u16* l) {
  __builtin_amdgcn_global_load_lds(
      (const __attribute__((address_space(1))) unsigned int*)g,
      (__attribute__((address_space(3))) unsigned int*)l, 16, 0, 0);
}

// ---------------- LayerNorm f32 -> f32 (final LN) ----------------
__global__ __launch_bounds__(256) void ln_f32(
    const float* __restrict__ src, float* __restrict__ dst,
    const float* __restrict__ scale, const float* __restrict__ bias)
{
  int r = blockIdx.x;
  int t = threadIdx.x;
  const float* sp = src + (size_t)r * cH;
  float4 x = ((const float4*)sp)[t];
  float s1 = x.x + x.y + x.z + x.w;
  float s2 = x.x * x.x + x.y * x.y + x.z * x.z + x.w * x.w;
  #pragma unroll
  for (int off = 32; off > 0; off >>= 1) {
    s1 += __shfl_down(s1, off);
    s2 += __shfl_down(s2, off);
  }
  __shared__ float w1[4], w2[4];
  __shared__ float stat[2];
  int wid = t >> 6, lid = t & 63;
  if (lid == 0) { w1[wid] = s1; w2[wid] = s2; }
  __syncthreads();
  if (t == 0) {
    float a = w1[0] + w1[1] + w1[2] + w1[3];
    float b = w2[0] + w2[1] + w2[2] + w2[3];
    float mu = a * (1.f / cH);
    float var = b * (1.f / cH) - mu * mu;
    if (var < 0.f) var = 0.f;
    stat[0] = mu; stat[1] = rsqrtf(var + cEPS);
  }
  __syncthreads();
  float mu = stat[0], rs = stat[1];
  int h0 = t * 4;
  float4 sc = *(const float4*)(scale + h0);
  float4 bi = *(const float4*)(bias + h0);
  float4 o;
  o.x = (x.x - mu) * rs * sc.x + bi.x;
  o.y = (x.y - mu) * rs * sc.y + bi.y;
  o.z = (x.z - mu) * rs * sc.z + bi.z;
  o.w = (x.w - mu) * rs * sc.w + bi.w;
  *(float4*)(dst + (size_t)r * cH + h0) = o;
}

// ---------------- LayerNorm f32 -> bf16 into kvin tail ----------------
__global__ __launch_bounds__(256) void ln_bf16(
    const float* __restrict__ src, u16* __restrict__ kvin,
    const float* __restrict__ scale, const float* __restrict__ bias)
{
  int r = blockIdx.x;            // 0..cB*cS-1
  int t = threadIdx.x;
  const float* sp = src + (size_t)r * cH;
  float4 x = ((const float4*)sp)[t];
  float s1 = x.x + x.y + x.z + x.w;
  float s2 = x.x * x.x + x.y * x.y + x.z * x.z + x.w * x.w;
  #pragma unroll
  for (int off = 32; off > 0; off >>= 1) {
    s1 += __shfl_down(s1, off);
    s2 += __shfl_down(s2, off);
  }
  __shared__ float w1[4], w2[4];
  __shared__ float stat[2];
  int wid = t >> 6, lid = t & 63;
  if (lid == 0) { w1[wid] = s1; w2[wid] = s2; }
  __syncthreads();
  if (t == 0) {
    float a = w1[0] + w1[1] + w1[2] + w1[3];
    float b = w2[0] + w2[1] + w2[2] + w2[3];
    float mu = a * (1.f / cH);
    float var = b * (1.f / cH) - mu * mu;
    if (var < 0.f) var = 0.f;
    stat[0] = mu; stat[1] = rsqrtf(var + cEPS);
  }
  __syncthreads();
  float mu = stat[0], rs = stat[1];
  int h0 = t * 4;
  float4 sc = *(const float4*)(scale + h0);
  float4 bi = *(const float4*)(bias + h0);
  int b = r >> 10, s = r & (cS - 1);
  u16* dp = kvin + ((size_t)(b * cL + cW * cS + s)) * cH + h0;
  ushort4 o; u16* op = (u16*)&o;
  op[0] = f2u((x.x - mu) * rs * sc.x + bi.x);
  op[1] = f2u((x.y - mu) * rs * sc.y + bi.y);
  op[2] = f2u((x.z - mu) * rs * sc.z + bi.z);
  op[3] = f2u((x.w - mu) * rs * sc.w + bi.w);
  *(ushort4*)dp = o;
}

// -------- cache f32 [W,B,S,H] -> kvin bf16 [B, w*S+s, H] --------
__global__ __launch_bounds__(256) void cache2kv(const float* __restrict__ cache,
                                                u16* __restrict__ kvin) {
  int blk = blockIdx.x;          // cB*cW*cS = 8192
  int b = blk >> 12, w = (blk >> 10) & 3, s = blk & 1023;
  const float* src = cache + ((size_t)((w * cB + b) * cS + s)) * cH;
  u16* dst = kvin + ((size_t)(b * cL + w * cS + s)) * cH;
  int t = threadIdx.x;
  float4 v = *(const float4*)(src + t * 4);
  ushort4 o; u16* op = (u16*)&o;
  op[0] = f2u(v.x); op[1] = f2u(v.y); op[2] = f2u(v.z); op[3] = f2u(v.w);
  *(ushort4*)(dst + t * 4) = o;
}

// -------- weight transpose: W f32 [k][n] -> Wt bf16 [n][k], 4 matrices --------
__global__ __launch_bounds__(256) void wtrans(
    const float* __restrict__ W0, const float* __restrict__ W1,
    const float* __restrict__ W2, const float* __restrict__ W3,
    u16* __restrict__ Wt)
{
  __shared__ float tile[32][33];
  int mat = blockIdx.z;
  const float* W = (mat == 0) ? W0 : (mat == 1) ? W1 : (mat == 2) ? W2 : W3;
  u16* out = Wt + (size_t)mat * cH * cH;
  int k0 = blockIdx.y * 32, n0 = blockIdx.x * 32;
  int t = threadIdx.x;
  int r = t >> 3, c = (t & 7) * 4;
  float4 v = *(const float4*)(W + (size_t)(k0 + r) * cH + n0 + c);
  tile[r][c] = v.x; tile[r][c + 1] = v.y; tile[r][c + 2] = v.z; tile[r][c + 3] = v.w;
  __syncthreads();
  ushort4 o; u16* op = (u16*)&o;
  #pragma unroll
  for (int j = 0; j < 4; j++) op[j] = f2u(tile[c + j][r]);
  *(ushort4*)(out + (size_t)(n0 + r) * cH + k0 + c) = o;
}

// ---------------- MFMA GEMM: C[M,1024] = A(bf16)[M,1024] @ W, Wt=[n][k] bf16 ----------------
constexpr int GBM = 128, GBN = 128, GLD = 40, TLD = 136;

__global__ __launch_bounds__(256) void mgemm(
    const u16* __restrict__ A, const u16* __restrict__ Wt,
    int a_rpb, int a_base, int a_stride,
    int c_rpb, int mode,
    u16* __restrict__ Cb,
    const float* __restrict__ hidden, const float* __restrict__ cachefull,
    const float* __restrict__ gate, const float* __restrict__ lsc,
    float* __restrict__ outp)
{
  __shared__ __align__(16) u16 smem[128 * TLD];
  u16* As = smem;              // [128][GLD]
  u16* Bs = smem + 128 * GLD;  // [128][GLD]

  int t = threadIdx.x;
  int m0 = blockIdx.y * GBM, n0 = blockIdx.x * GBN;
  int wave = t >> 6, lane = t & 63, l15 = lane & 15, quad = lane >> 4;
  int wm = (wave >> 1) * 64, wn = (wave & 1) * 64;

  int sr = t >> 2, sk = (t & 3) * 8;
  int rg0 = m0 + sr, rg1 = rg0 + 64;
  int ab0 = rg0 / a_rpb, ab1 = rg1 / a_rpb;
  const u16* arow0 = A + (size_t)(ab0 * a_stride + a_base + (rg0 - ab0 * a_rpb)) * cH + sk;
  const u16* arow1 = A + (size_t)(ab1 * a_stride + a_base + (rg1 - ab1 * a_rpb)) * cH + sk;
  const u16* wrow0 = Wt + (size_t)(n0 + sr) * cH + sk;
  const u16* wrow1 = Wt + (size_t)(n0 + sr + 64) * cH + sk;

  f32x4 acc[4][4] = {};

  for (int k0 = 0; k0 < cH; k0 += 32) {
    uint4 a0 = *(const uint4*)(arow0 + k0);
    uint4 a1 = *(const uint4*)(arow1 + k0);
    uint4 b0 = *(const uint4*)(wrow0 + k0);
    uint4 b1 = *(const uint4*)(wrow1 + k0);
    __syncthreads();
    *(uint4*)&As[sr * GLD + sk] = a0;
    *(uint4*)&As[(sr + 64) * GLD + sk] = a1;
    *(uint4*)&Bs[sr * GLD + sk] = b0;
    *(uint4*)&Bs[(sr + 64) * GLD + sk] = b1;
    __syncthreads();
    s16x8 af[4], bf[4];
    #pragma unroll
    for (int mt = 0; mt < 4; mt++)
      af[mt] = *(const s16x8*)&As[(wm + mt * 16 + l15) * GLD + quad * 8];
    #pragma unroll
    for (int nt = 0; nt < 4; nt++)
      bf[nt] = *(const s16x8*)&Bs[(wn + nt * 16 + l15) * GLD + quad * 8];
    #pragma unroll
    for (int mt = 0; mt < 4; mt++)
      #pragma unroll
      for (int nt = 0; nt < 4; nt++)
        acc[mt][nt] = __builtin_amdgcn_mfma_f32_16x16x32_bf16(af[mt], bf[nt], acc[mt][nt], 0, 0, 0);
  }

  if (mode == 1) {
    #pragma unroll
    for (int mt = 0; mt < 4; mt++)
      #pragma unroll
      for (int i = 0; i < 4; i++) {
        int rg = m0 + wm + mt * 16 + quad * 4 + i;
        int bo = rg / c_rpb, lo = rg - bo * c_rpb;
        #pragma unroll
        for (int nt = 0; nt < 4; nt++) {
          int n = n0 + wn + nt * 16 + l15;
          int h = n >> 6, d = n & 63;
          Cb[(((size_t)(bo * cNH + h) * c_rpb + lo) * cHD) + d] = f2u(acc[mt][nt][i]);
        }
      }
  } else if (mode == 3) {
    u16* t2 = smem;
    __syncthreads();
    #pragma unroll
    for (int mt = 0; mt < 4; mt++)
      #pragma unroll
      for (int nt = 0; nt < 4; nt++) {
        ushort4 o; u16* op = (u16*)&o;
        #pragma unroll
        for (int i = 0; i < 4; i++) op[i] = f2u(acc[mt][nt][i]);
        *(ushort4*)&t2[(size_t)(wn + nt * 16 + l15) * TLD + wm + mt * 16 + quad * 4] = o;
      }
    __syncthreads();
    int n_l = t >> 1, mh = (t & 1) * 64;
    int bo = m0 / c_rpb;
    int lo = m0 - bo * c_rpb + mh;
    int n = n0 + n_l, h = n >> 6, d = n & 63;
    u16* dst = Cb + ((size_t)(bo * cNH + h) * cHD + d) * (size_t)c_rpb + lo;
    #pragma unroll
    for (int j = 0; j < 8; j++)
      *(uint4*)(dst + j * 8) = *(const uint4*)&t2[(size_t)n_l * TLD + mh + j * 8];
  } else {
    float gv[4], lv[4];
    #pragma unroll
    for (int nt = 0; nt < 4; nt++) {
      int n = n0 + wn + nt * 16 + l15;
      gv[nt] = 1.f / (1.f + __expf(-gate[n]));
      lv[nt] = lsc[n];
    }
    #pragma unroll
    for (int mt = 0; mt < 4; mt++)
      #pragma unroll
      for (int i = 0; i < 4; i++) {
        int rg = m0 + wm + mt * 16 + quad * 4 + i;
        size_t rbase = (size_t)rg * cH;
        #pragma unroll
        for (int nt = 0; nt < 4; nt++) {
          int n = n0 + wn + nt * 16 + l15;
          float hid = hidden[rbase + n];
          float cr = cachefull[(size_t)3 * cB * cS * cH + rbase + n];
          outp[rbase + n] = hid + lv[nt] * (gv[nt] * acc[mt][nt][i] + (1.f - gv[nt]) * cr);
        }
      }
  }
}

// ---------------- RoPE in-place on head-major bf16 [b*h][rows][64] ----------------
__global__ __launch_bounds__(256) void rope_b16(u16* __restrict__ X, int rows) {
  size_t idx = (size_t)blockIdx.x * 256 + threadIdx.x;
  int d = (int)(idx & 31);
  size_t rest = idx >> 5;
  int row = (int)(rest % rows);
  size_t bh = rest / rows;
  u16* xp = X + (bh * rows + row) * cHD;
  int pos = row & (cS - 1);
  float freq = exp2f(-(float)d * (13.287712379549449f / 32.f)); // 10000^(-d/32)
  float ang = (float)pos * freq;
  float sn, cs;
  sincosf(ang, &sn, &cs);
  float x1 = u2f(xp[d]), x2 = u2f(xp[d + 32]);
  xp[d] = f2u(x1 * cs - x2 * sn);
  xp[d + 32] = f2u(x1 * sn + x2 * cs);
}

// ---------------- MFMA flash attention, split-K over key quarters ----------------
// K tiles staged in LDS (double-buffered, XOR-swizzled, global_load_lds,
// counted vmcnt, raw barriers).  All 4 waves of a block share the K tile.
constexpr int ACK = 64;
constexpr int PLD = 72;
constexpr int KSPLIT = 4;
constexpr int KS = cL / KSPLIT;      // 1280 keys per split
constexpr int NIT = KS / ACK;        // 20 tiles
constexpr int NRB = cB * cNH * cS;   // rows per split (32768)

__global__ __launch_bounds__(256, 4) void attn_mfma(
    const u16* __restrict__ Q, const u16* __restrict__ K, const u16* __restrict__ Vt,
    float* __restrict__ o0, float* __restrict__ o1,
    float* __restrict__ o2, float* __restrict__ o3,
    float* __restrict__ mlbuf)
{
  // 2 x (64 keys x 64 d) bf16 = 2 x 8 KB, XOR-swizzled: phys = log ^ ((row&7)<<4)
  __shared__ __align__(16) u16 kls[2][ACK * cHD];
  __shared__ u16 pbuf[4][16 * PLD];

  int t = threadIdx.x;
  int wave = t >> 6, lane = t & 63;
  int l15 = lane & 15, quad = lane >> 4;
  int qt = blockIdx.x, h = blockIdx.y;
  int bz = blockIdx.z;
  int b = bz & (cB - 1), split = bz >> 1;
  int q0 = qt * 64 + wave * 16;
  int kbase = split * KS;

  const u16* qp = Q + ((size_t)(b * cNH + h) * cS + q0) * cHD;
  const char* kp = (const char*)(K + ((size_t)(b * cNH + h) * cL + kbase) * cHD);
  const u16* vp = Vt + (size_t)(b * cNH + h) * cHD * cL + kbase;
  u16* pw = pbuf[wave];

  // staging geometry: thread covers phys bytes P0 and P0+4096 of the 8 KB tile;
  // source is pre-swizzled so swizzled reads see logical layout (involution).
  int P0 = wave * 1024 + lane * 16;
  int P1 = P0 + 4096;
  int s0 = P0 ^ (((P0 >> 7) & 7) << 4);
  int s1 = P1 ^ (((P1 >> 7) & 7) << 4);
  // swizzled fragment column offsets for ds_read_b128 (row&7 == l15&7)
  int fsw0 = (quad * 16) ^ ((l15 & 7) << 4);
  int fsw1 = (64 + quad * 16) ^ ((l15 & 7) << 4);

  s16x8 qf0 = ld_frag(qp + (size_t)l15 * cHD + quad * 8);
  s16x8 qf1 = ld_frag(qp + (size_t)l15 * cHD + 32 + quad * 8);

  // prologue: stage tile 0 into buffer 0
  gl_lds16((const u16*)(kp + s0), (u16*)((char*)&kls[0][0] + wave * 1024));
  gl_lds16((const u16*)(kp + s1), (u16*)((char*)&kls[0][0] + 4096 + wave * 1024));

  f32x4 oacc[4] = {};
  float mrow[4], lrow[4];
  #pragma unroll
  for (int i = 0; i < 4; i++) { mrow[i] = -1e30f; lrow[i] = 0.f; }

  constexpr float SCL = 0.125f * 1.4426950408889634f;

  for (int kt = 0; kt < NIT; kt++) {
    int cur = kt & 1;
    // ---- V loads for this tile (latency covered by QK+softmax below) ----
    uint4 vreg[8];
    #pragma unroll
    for (int dt = 0; dt < 4; dt++) {
      const u16* vr = vp + (size_t)(dt * 16 + l15) * cL + kt * ACK;
      vreg[2 * dt]     = *(const uint4*)(vr + quad * 8);
      vreg[2 * dt + 1] = *(const uint4*)(vr + 32 + quad * 8);
    }
    // ---- barrier A: all waves done reading kls[cur^1] (prev iter) ----
    asm volatile("" ::: "memory");
    __builtin_amdgcn_s_barrier();
    asm volatile("" ::: "memory");
    // ---- stage next tile into kls[cur^1] ----
    int nk = kt + 1; if (nk == NIT) nk = 0;
    const char* kn = kp + (size_t)nk * (ACK * cHD * 2);
    gl_lds16((const u16*)(kn + s0), (u16*)((char*)&kls[cur ^ 1][0] + wave * 1024));
    gl_lds16((const u16*)(kn + s1), (u16*)((char*)&kls[cur ^ 1][0] + 4096 + wave * 1024));
    // ---- wait own stage of tile kt (10 newer ops: 8 V + 2 stage-next) ----
    asm volatile("s_waitcnt vmcnt(10)" ::: "memory");
    __builtin_amdgcn_s_barrier();
    asm volatile("" ::: "memory");
    // ---- QK^T from LDS (swizzled reads, conflict-free) ----
    const char* kc = (const char*)&kls[cur][0];
    f32x4 sc[4];
    #pragma unroll
    for (int nt = 0; nt < 4; nt++) {
      s16x8 kf0 = *(const s16x8*)(kc + (nt * 16 + l15) * 128 + fsw0);
      s16x8 kf1 = *(const s16x8*)(kc + (nt * 16 + l15) * 128 + fsw1);
      f32x4 a = {};
      a = __builtin_amdgcn_mfma_f32_16x16x32_bf16(qf0, kf0, a, 0, 0, 0);
      a = __builtin_amdgcn_mfma_f32_16x16x32_bf16(qf1, kf1, a, 0, 0, 0);
      sc[nt] = a * SCL;
    }
    // ---- online softmax (deferred l-reduce, skip-rescale when max unchanged) ----
    float mx[4];
    #pragma unroll
    for (int i = 0; i < 4; i++)
      mx[i] = fmaxf(fmaxf(sc[0][i], sc[1][i]), fmaxf(sc[2][i], sc[3][i]));
    #pragma unroll
    for (int off = 1; off < 16; off <<= 1)
      #pragma unroll
      for (int i = 0; i < 4; i++) mx[i] = fmaxf(mx[i], __shfl_xor(mx[i], off));
    bool need = (mx[0] > mrow[0]) | (mx[1] > mrow[1]) |
                (mx[2] > mrow[2]) | (mx[3] > mrow[3]);
    if (__any(need)) {
      float alpha[4];
      #pragma unroll
      for (int i = 0; i < 4; i++) {
        float mn = fmaxf(mrow[i], mx[i]);
        alpha[i] = exp2f(mrow[i] - mn);
        mrow[i] = mn;
        lrow[i] *= alpha[i];
      }
      #pragma unroll
      for (int dt = 0; dt < 4; dt++)
        #pragma unroll
        for (int i = 0; i < 4; i++) oacc[dt][i] *= alpha[i];
    }
    float ps[4] = {};
    #pragma unroll
    for (int nt = 0; nt < 4; nt++)
      #pragma unroll
      for (int i = 0; i < 4; i++) {
        float p = exp2f(sc[nt][i] - mrow[i]);
        ps[i] += p;
        pw[(quad * 4 + i) * PLD + nt * 16 + l15] = f2u(p);
      }
    #pragma unroll
    for (int i = 0; i < 4; i++) lrow[i] += ps[i];   // per-lane partial; reduced once at end
    // ---- PV ----
    s16x8 pf0 = *(const s16x8*)&pw[l15 * PLD + quad * 8];
    s16x8 pf1 = *(const s16x8*)&pw[l15 * PLD + 32 + quad * 8];
    #pragma unroll
    for (int dt = 0; dt < 4; dt++) {
      oacc[dt] = __builtin_amdgcn_mfma_f32_16x16x32_bf16(pf0, u4_frag(vreg[2 * dt]), oacc[dt], 0, 0, 0);
      oacc[dt] = __builtin_amdgcn_mfma_f32_16x16x32_bf16(pf1, u4_frag(vreg[2 * dt + 1]), oacc[dt], 0, 0, 0);
    }
  }
  // ---- final l-reduce across the 16-lane key group ----
  #pragma unroll
  for (int off = 1; off < 16; off <<= 1)
    #pragma unroll
    for (int i = 0; i < 4; i++) lrow[i] += __shfl_xor(lrow[i], off);
  // ---- epilogue: unnormalized partial O + (m,l) ----
  float* ob = (split == 0) ? o0 : (split == 1) ? o1 : (split == 2) ? o2 : o3;
  #pragma unroll
  for (int i = 0; i < 4; i++) {
    int q = q0 + quad * 4 + i;
    size_t Rl = (size_t)(b * cNH + h) * cS + q;
    float* orow = ob + Rl * cHD;
    #pragma unroll
    for (int dt = 0; dt < 4; dt++)
      orow[dt * 16 + l15] = oacc[dt][i];
    if (l15 == 0) {
      mlbuf[((size_t)split * NRB + Rl) * 2] = mrow[i];
      mlbuf[((size_t)split * NRB + Rl) * 2 + 1] = lrow[i];
    }
  }
}

// ---------------- split-K merge: combine four softmax partials -> bf16 ctx ----------------
__global__ __launch_bounds__(256) void attn_merge(
    const float* __restrict__ o0, const float* __restrict__ o1,
    const float* __restrict__ o2, const float* __restrict__ o3,
    const float* __restrict__ mlbuf, u16* __restrict__ ctx)
{
  int t = threadIdx.x;
  int R = blockIdx.x * 4 + (t >> 6);   // (b*cNH+h)*cS + q
  int d = t & 63;
  float ms[KSPLIT], ls[KSPLIT];
  float m = -1e30f;
  #pragma unroll
  for (int s = 0; s < KSPLIT; s++) {
    ms[s] = mlbuf[((size_t)s * NRB + R) * 2];
    ls[s] = mlbuf[((size_t)s * NRB + R) * 2 + 1];
    m = fmaxf(m, ms[s]);
  }
  const float* ops[KSPLIT] = {o0, o1, o2, o3};
  float num = 0.f, den = 0.f;
  #pragma unroll
  for (int s = 0; s < KSPLIT; s++) {
    float a = exp2f(ms[s] - m);
    num += ops[s][(size_t)R * cHD + d] * a;
    den += ls[s] * a;
  }
  float val = num / den;
  int q = R & (cS - 1), h = (R >> 10) & 15, b = R >> 14;
  ctx[((size_t)b * cS + q) * cH + h * cHD + d] = f2u(val);
}

extern "C" void kernel_launch(void* const* d_in, const int* in_sizes, int n_in,
                              void* d_out, int out_size, void* d_ws, size_t ws_size,
                              hipStream_t stream)
{
  const float* hidden = (const float*)d_in[0];
  const float* cache  = (const float*)d_in[1];
  const float* ln_s   = (const float*)d_in[2];
  const float* ln_b   = (const float*)d_in[3];
  const float* Wq     = (const float*)d_in[4];
  const float* Wk     = (const float*)d_in[5];
  const float* Wv     = (const float*)d_in[6];
  const float* Wo     = (const float*)d_in[7];
  const float* gate   = (const float*)d_in[8];
  const float* lsc    = (const float*)d_in[9];
  float* outp = (float*)d_out;

  // ws: kvin 20.97M | vt 20.97M | opart(splits 0,1) 16.78M  (~58.7 MB)
  u16* kvin = (u16*)d_ws;
  u16* vt   = kvin + (size_t)cB * cL * cH;
  float* opart = (float*)(vt + (size_t)cB * cL * cH);
  float* o0 = opart;
  float* o1 = opart + (size_t)cB * cNH * cS * cHD;          // +8.39MB
  // aliases into kvin (dead rows by the time these are written):
  u16* qb  = kvin;                                // [0, 4.19M) written by Q GEMM (last kvin reader)
  u16* ctx = kvin + (size_t)2 * 1024 * 1024;      // [4.19M, 8.39M) written by attn_merge
  float* o2 = (float*)(kvin + (size_t)4 * 1024 * 1024);   // bytes [8.39M, 16.78M)
  float* mlbuf = (float*)(kvin + (size_t)8 * 1024 * 1024);// bytes [16.78M, 17.83M), 4 splits
  // split-3 opart parked in d_out output region [0, 8.39M) — written by attn,
  // read by merge, then overwritten by the step-7 GEMM epilogue:
  float* o3 = outp;
  // scratch parked in d_out (overwritten by memcpy/final-LN at the end):
  u16* kb = (u16*)(outp + (size_t)cB * cS * cH);
  u16* Wt = (u16*)(outp + (size_t)(1 + 3) * cB * cS * cH);
  u16* Wt_q = Wt;
  u16* Wt_k = Wt + (size_t)cH * cH;
  u16* Wt_v = Wt + (size_t)2 * cH * cH;
  u16* Wt_o = Wt + (size_t)3 * cH * cH;

  // 1) weight transpose+convert
  wtrans<<<dim3(32, 32, 4), 256, 0, stream>>>(Wq, Wk, Wv, Wo, Wt);
  // 2) cache -> kvin head rows (bf16, permuted)
  cache2kv<<<cB * cW * cS, 256, 0, stream>>>(cache, kvin);
  // 3) pre-norm -> kvin tail rows (bf16)
  ln_bf16<<<cB * cS, 256, 0, stream>>>(hidden, kvin, ln_s, ln_b);

  // 4) K/V/Q projections (MFMA)
  mgemm<<<dim3(8, (cB * cL) / GBM), 256, 0, stream>>>(
      kvin, Wt_k, cL, 0, cL, cL, 1, kb, nullptr, nullptr, nullptr, nullptr, nullptr);
  mgemm<<<dim3(8, (cB * cL) / GBM), 256, 0, stream>>>(
      kvin, Wt_v, cL, 0, cL, cL, 3, vt, nullptr, nullptr, nullptr, nullptr, nullptr);
  mgemm<<<dim3(8, (cB * cS) / GBM), 256, 0, stream>>>(
      kvin, Wt_q, cS, cW * cS, cL, cS, 1, qb, nullptr, nullptr, nullptr, nullptr, nullptr);

  // 5) RoPE on Q and K
  rope_b16<<<(cB * cNH * cS * 32) / 256, 256, 0, stream>>>(qb, cS);
  rope_b16<<<(cB * cNH * cL * 32) / 256, 256, 0, stream>>>(kb, cL);

  // 6) 4-way split-K MFMA flash attention -> partials, then merge -> ctx (bf16)
  attn_mfma<<<dim3(cS / 64, cNH, cB * KSPLIT), 256, 0, stream>>>(
      qb, kb, vt, o0, o1, o2, o3, mlbuf);
  attn_merge<<<(cB * cNH * cS) / 4, 256, 0, stream>>>(o0, o1, o2, o3, mlbuf, ctx);

  // 7) ctx @ Wo with fused gated residual -> output f32
  mgemm<<<dim3(8, (cB * cS) / GBM), 256, 0, stream>>>(
      ctx, Wt_o, cB * cS, 0, cB * cS, cB * cS, 2, nullptr,
      hidden, cache, gate, lsc, outp);

  // 8) new_cache[0:3] = cache[1:4]
  hipMemcpyAsync(outp + (size_t)cB * cS * cH, cache + (size_t)cB * cS * cH,
                 (size_t)(cW - 1) * cB * cS * cH * sizeof(float),
                 hipMemcpyDeviceToDevice, stream);
  // 9) final layernorm -> new_cache slot 3
  ln_f32<<<cB * cS, 256, 0, stream>>>(outp, outp + (size_t)cW * cB * cS * cH, ln_s, ln_b);
}

// Round 5
// 482.916 us; speedup vs baseline: 1.5901x; 1.0575x over previous
//
#include <hip/hip_runtime.h>
#include <math.h>

typedef unsigned short u16;

constexpr int cB = 2;
constexpr int cS = 1024;
constexpr int cH = 1024;
constexpr int cNH = 16;
constexpr int cHD = 64;
constexpr int cW = 4;
constexpr int cL = (cW + 1) * cS; // 5120
constexpr float cEPS = 1e-5f;

typedef short s16x8 __attribute__((ext_vector_type(8)));   // 8 bf16 (4 VGPRs)
typedef float f32x4 __attribute__((ext_vector_type(4)));   // MFMA C/D

__device__ __forceinline__ float u2f(u16 u) {
  union { unsigned int i; float f; } x; x.i = ((unsigned int)u) << 16; return x.f;
}
__device__ __forceinline__ u16 f2u(float f) {
  union { float f; unsigned int i; } x; x.f = f;
  unsigned int i = x.i;
  i += 0x7fffu + ((i >> 16) & 1u); // RNE
  return (u16)(i >> 16);
}
// fast path: native v_cvt bf16 (RNE), 1 VALU op
__device__ __forceinline__ u16 f2u_rt(float f) {
  union { __bf16 b; u16 u; } c; c.b = (__bf16)f; return c.u;
}
__device__ __forceinline__ s16x8 ld_frag(const u16* p) {
  uint4 v = *(const uint4*)p;
  union { uint4 u; s16x8 s; } c; c.u = v; return c.s;
}
__device__ __forceinline__ s16x8 u4_frag(uint4 v) {
  union { uint4 u; s16x8 s; } c; c.u = v; return c.s;
}
// async 16B global -> LDS (dest = wave-uniform base + lane*16)
__device__ __forceinline__ void gl_lds16(const u16* g, u16* l) {
  __builtin_amdgcn_global_load_lds(
      (const __attribute__((address_space(1))) unsigned int*)g,
      (__attribute__((address_space(3))) unsigned int*)l, 16, 0, 0);
}
// VALU-pipe cross-lane fmax via DPP (ctrl must be a literal -> template param)
template <int CTRL>
__device__ __forceinline__ float dpp_fmax(float x) {
  union { float f; int i; } a, r;
  a.f = x;
  r.i = __builtin_amdgcn_update_dpp(a.i, a.i, CTRL, 0xF, 0xF, true);
  return fmaxf(x, r.f);
}

// ---------------- LayerNorm f32 -> f32 (final LN) ----------------
__global__ __launch_bounds__(256) void ln_f32(
    const float* __restrict__ src, float* __restrict__ dst,
    const float* __restrict__ scale, const float* __restrict__ bias)
{
  int r = blockIdx.x;
  int t = threadIdx.x;
  const float* sp = src + (size_t)r * cH;
  float4 x = ((const float4*)sp)[t];
  float s1 = x.x + x.y + x.z + x.w;
  float s2 = x.x * x.x + x.y * x.y + x.z * x.z + x.w * x.w;
  #pragma unroll
  for (int off = 32; off > 0; off >>= 1) {
    s1 += __shfl_down(s1, off);
    s2 += __shfl_down(s2, off);
  }
  __shared__ float w1[4], w2[4];
  __shared__ float stat[2];
  int wid = t >> 6, lid = t & 63;
  if (lid == 0) { w1[wid] = s1; w2[wid] = s2; }
  __syncthreads();
  if (t == 0) {
    float a = w1[0] + w1[1] + w1[2] + w1[3];
    float b = w2[0] + w2[1] + w2[2] + w2[3];
    float mu = a * (1.f / cH);
    float var = b * (1.f / cH) - mu * mu;
    if (var < 0.f) var = 0.f;
    stat[0] = mu; stat[1] = rsqrtf(var + cEPS);
  }
  __syncthreads();
  float mu = stat[0], rs = stat[1];
  int h0 = t * 4;
  float4 sc = *(const float4*)(scale + h0);
  float4 bi = *(const float4*)(bias + h0);
  float4 o;
  o.x = (x.x - mu) * rs * sc.x + bi.x;
  o.y = (x.y - mu) * rs * sc.y + bi.y;
  o.z = (x.z - mu) * rs * sc.z + bi.z;
  o.w = (x.w - mu) * rs * sc.w + bi.w;
  *(float4*)(dst + (size_t)r * cH + h0) = o;
}

// ---------------- LayerNorm f32 -> bf16 into kvin tail ----------------
__global__ __launch_bounds__(256) void ln_bf16(
    const float* __restrict__ src, u16* __restrict__ kvin,
    const float* __restrict__ scale, const float* __restrict__ bias)
{
  int r = blockIdx.x;            // 0..cB*cS-1
  int t = threadIdx.x;
  const float* sp = src + (size_t)r * cH;
  float4 x = ((const float4*)sp)[t];
  float s1 = x.x + x.y + x.z + x.w;
  float s2 = x.x * x.x + x.y * x.y + x.z * x.z + x.w * x.w;
  #pragma unroll
  for (int off = 32; off > 0; off >>= 1) {
    s1 += __shfl_down(s1, off);
    s2 += __shfl_down(s2, off);
  }
  __shared__ float w1[4], w2[4];
  __shared__ float stat[2];
  int wid = t >> 6, lid = t & 63;
  if (lid == 0) { w1[wid] = s1; w2[wid] = s2; }
  __syncthreads();
  if (t == 0) {
    float a = w1[0] + w1[1] + w1[2] + w1[3];
    float b = w2[0] + w2[1] + w2[2] + w2[3];
    float mu = a * (1.f / cH);
    float var = b * (1.f / cH) - mu * mu;
    if (var < 0.f) var = 0.f;
    stat[0] = mu; stat[1] = rsqrtf(var + cEPS);
  }
  __syncthreads();
  float mu = stat[0], rs = stat[1];
  int h0 = t * 4;
  float4 sc = *(const float4*)(scale + h0);
  float4 bi = *(const float4*)(bias + h0);
  int b = r >> 10, s = r & (cS - 1);
  u16* dp = kvin + ((size_t)(b * cL + cW * cS + s)) * cH + h0;
  ushort4 o; u16* op = (u16*)&o;
  op[0] = f2u((x.x - mu) * rs * sc.x + bi.x);
  op[1] = f2u((x.y - mu) * rs * sc.y + bi.y);
  op[2] = f2u((x.z - mu) * rs * sc.z + bi.z);
  op[3] = f2u((x.w - mu) * rs * sc.w + bi.w);
  *(ushort4*)dp = o;
}

// -------- cache f32 [W,B,S,H] -> kvin bf16 [B, w*S+s, H] --------
__global__ __launch_bounds__(256) void cache2kv(const float* __restrict__ cache,
                                                u16* __restrict__ kvin) {
  int blk = blockIdx.x;          // cB*cW*cS = 8192
  int b = blk >> 12, w = (blk >> 10) & 3, s = blk & 1023;
  const float* src = cache + ((size_t)((w * cB + b) * cS + s)) * cH;
  u16* dst = kvin + ((size_t)(b * cL + w * cS + s)) * cH;
  int t = threadIdx.x;
  float4 v = *(const float4*)(src + t * 4);
  ushort4 o; u16* op = (u16*)&o;
  op[0] = f2u(v.x); op[1] = f2u(v.y); op[2] = f2u(v.z); op[3] = f2u(v.w);
  *(ushort4*)(dst + t * 4) = o;
}

// -------- weight transpose: W f32 [k][n] -> Wt bf16 [n][k], 4 matrices --------
__global__ __launch_bounds__(256) void wtrans(
    const float* __restrict__ W0, const float* __restrict__ W1,
    const float* __restrict__ W2, const float* __restrict__ W3,
    u16* __restrict__ Wt)
{
  __shared__ float tile[32][33];
  int mat = blockIdx.z;
  const float* W = (mat == 0) ? W0 : (mat == 1) ? W1 : (mat == 2) ? W2 : W3;
  u16* out = Wt + (size_t)mat * cH * cH;
  int k0 = blockIdx.y * 32, n0 = blockIdx.x * 32;
  int t = threadIdx.x;
  int r = t >> 3, c = (t & 7) * 4;
  float4 v = *(const float4*)(W + (size_t)(k0 + r) * cH + n0 + c);
  tile[r][c] = v.x; tile[r][c + 1] = v.y; tile[r][c + 2] = v.z; tile[r][c + 3] = v.w;
  __syncthreads();
  ushort4 o; u16* op = (u16*)&o;
  #pragma unroll
  for (int j = 0; j < 4; j++) op[j] = f2u(tile[c + j][r]);
  *(ushort4*)(out + (size_t)(n0 + r) * cH + k0 + c) = o;
}

// ---------------- MFMA GEMM: C[M,1024] = A(bf16)[M,1024] @ W, Wt=[n][k] bf16 ----------------
// mode 5: fused K|V projection — Wt spans 2048 rows (Wk then Wv); n0<1024 -> K
// epilogue (mode1 -> Cb), n0>=1024 -> V epilogue (mode3 -> Cb2, n-1024).
constexpr int GBM = 128, GBN = 128, GLD = 40, TLD = 136;

__global__ __launch_bounds__(256) void mgemm(
    const u16* __restrict__ A, const u16* __restrict__ Wt,
    int a_rpb, int a_base, int a_stride,
    int c_rpb, int mode,
    u16* __restrict__ Cb, u16* __restrict__ Cb2,
    const float* __restrict__ hidden, const float* __restrict__ cachefull,
    const float* __restrict__ gate, const float* __restrict__ lsc,
    float* __restrict__ outp)
{
  __shared__ __align__(16) u16 smem[128 * TLD];
  u16* As = smem;              // [128][GLD]
  u16* Bs = smem + 128 * GLD;  // [128][GLD]

  int t = threadIdx.x;
  int m0 = blockIdx.y * GBM, n0 = blockIdx.x * GBN;
  int wave = t >> 6, lane = t & 63, l15 = lane & 15, quad = lane >> 4;
  int wm = (wave >> 1) * 64, wn = (wave & 1) * 64;

  int sr = t >> 2, sk = (t & 3) * 8;
  int rg0 = m0 + sr, rg1 = rg0 + 64;
  int ab0 = rg0 / a_rpb, ab1 = rg1 / a_rpb;
  const u16* arow0 = A + (size_t)(ab0 * a_stride + a_base + (rg0 - ab0 * a_rpb)) * cH + sk;
  const u16* arow1 = A + (size_t)(ab1 * a_stride + a_base + (rg1 - ab1 * a_rpb)) * cH + sk;
  const u16* wrow0 = Wt + (size_t)(n0 + sr) * cH + sk;
  const u16* wrow1 = Wt + (size_t)(n0 + sr + 64) * cH + sk;

  f32x4 acc[4][4] = {};

  for (int k0 = 0; k0 < cH; k0 += 32) {
    uint4 a0 = *(const uint4*)(arow0 + k0);
    uint4 a1 = *(const uint4*)(arow1 + k0);
    uint4 b0 = *(const uint4*)(wrow0 + k0);
    uint4 b1 = *(const uint4*)(wrow1 + k0);
    __syncthreads();
    *(uint4*)&As[sr * GLD + sk] = a0;
    *(uint4*)&As[(sr + 64) * GLD + sk] = a1;
    *(uint4*)&Bs[sr * GLD + sk] = b0;
    *(uint4*)&Bs[(sr + 64) * GLD + sk] = b1;
    __syncthreads();
    s16x8 af[4], bf[4];
    #pragma unroll
    for (int mt = 0; mt < 4; mt++)
      af[mt] = *(const s16x8*)&As[(wm + mt * 16 + l15) * GLD + quad * 8];
    #pragma unroll
    for (int nt = 0; nt < 4; nt++)
      bf[nt] = *(const s16x8*)&Bs[(wn + nt * 16 + l15) * GLD + quad * 8];
    #pragma unroll
    for (int mt = 0; mt < 4; mt++)
      #pragma unroll
      for (int nt = 0; nt < 4; nt++)
        acc[mt][nt] = __builtin_amdgcn_mfma_f32_16x16x32_bf16(af[mt], bf[nt], acc[mt][nt], 0, 0, 0);
  }

  int mode_eff = mode;
  u16* Cout = Cb;
  int nbase = n0;
  if (mode == 5) {
    if (n0 < cH) { mode_eff = 1; }
    else { mode_eff = 3; Cout = Cb2; nbase = n0 - cH; }
  }

  if (mode_eff == 1) {
    #pragma unroll
    for (int mt = 0; mt < 4; mt++)
      #pragma unroll
      for (int i = 0; i < 4; i++) {
        int rg = m0 + wm + mt * 16 + quad * 4 + i;
        int bo = rg / c_rpb, lo = rg - bo * c_rpb;
        #pragma unroll
        for (int nt = 0; nt < 4; nt++) {
          int n = nbase + wn + nt * 16 + l15;
          int h = n >> 6, d = n & 63;
          Cout[(((size_t)(bo * cNH + h) * c_rpb + lo) * cHD) + d] = f2u(acc[mt][nt][i]);
        }
      }
  } else if (mode_eff == 3) {
    u16* t2 = smem;
    __syncthreads();
    #pragma unroll
    for (int mt = 0; mt < 4; mt++)
      #pragma unroll
      for (int nt = 0; nt < 4; nt++) {
        ushort4 o; u16* op = (u16*)&o;
        #pragma unroll
        for (int i = 0; i < 4; i++) op[i] = f2u(acc[mt][nt][i]);
        *(ushort4*)&t2[(size_t)(wn + nt * 16 + l15) * TLD + wm + mt * 16 + quad * 4] = o;
      }
    __syncthreads();
    int n_l = t >> 1, mh = (t & 1) * 64;
    int bo = m0 / c_rpb;
    int lo = m0 - bo * c_rpb + mh;
    int n = nbase + n_l, h = n >> 6, d = n & 63;
    u16* dst = Cout + ((size_t)(bo * cNH + h) * cHD + d) * (size_t)c_rpb + lo;
    #pragma unroll
    for (int j = 0; j < 8; j++)
      *(uint4*)(dst + j * 8) = *(const uint4*)&t2[(size_t)n_l * TLD + mh + j * 8];
  } else {
    float gv[4], lv[4];
    #pragma unroll
    for (int nt = 0; nt < 4; nt++) {
      int n = n0 + wn + nt * 16 + l15;
      gv[nt] = 1.f / (1.f + __expf(-gate[n]));
      lv[nt] = lsc[n];
    }
    #pragma unroll
    for (int mt = 0; mt < 4; mt++)
      #pragma unroll
      for (int i = 0; i < 4; i++) {
        int rg = m0 + wm + mt * 16 + quad * 4 + i;
        size_t rbase = (size_t)rg * cH;
        #pragma unroll
        for (int nt = 0; nt < 4; nt++) {
          int n = n0 + wn + nt * 16 + l15;
          float hid = hidden[rbase + n];
          float cr = cachefull[(size_t)3 * cB * cS * cH + rbase + n];
          outp[rbase + n] = hid + lv[nt] * (gv[nt] * acc[mt][nt][i] + (1.f - gv[nt]) * cr);
        }
      }
  }
}

// ---------------- RoPE in-place on head-major bf16 [b*h][rows][64] ----------------
__global__ __launch_bounds__(256) void rope_b16(u16* __restrict__ X, int rows) {
  size_t idx = (size_t)blockIdx.x * 256 + threadIdx.x;
  int d = (int)(idx & 31);
  size_t rest = idx >> 5;
  int row = (int)(rest % rows);
  size_t bh = rest / rows;
  u16* xp = X + (bh * rows + row) * cHD;
  int pos = row & (cS - 1);
  float freq = exp2f(-(float)d * (13.287712379549449f / 32.f)); // 10000^(-d/32)
  float ang = (float)pos * freq;
  float sn, cs;
  sincosf(ang, &sn, &cs);
  float x1 = u2f(xp[d]), x2 = u2f(xp[d + 32]);
  xp[d] = f2u(x1 * cs - x2 * sn);
  xp[d + 32] = f2u(x1 * sn + x2 * cs);
}

// ---------------- MFMA flash attention, split-K over key quarters ----------------
// K tiles staged in LDS (double-buffered, XOR-swizzled, global_load_lds,
// counted vmcnt, raw barriers).  All 4 waves of a block share the K tile.
constexpr int ACK = 64;
constexpr int PLD = 72;
constexpr int KSPLIT = 4;
constexpr int KS = cL / KSPLIT;      // 1280 keys per split
constexpr int NIT = KS / ACK;        // 20 tiles
constexpr int NRB = cB * cNH * cS;   // rows per split (32768)

__global__ __launch_bounds__(256, 4) void attn_mfma(
    const u16* __restrict__ Q, const u16* __restrict__ K, const u16* __restrict__ Vt,
    float* __restrict__ o0, float* __restrict__ o1,
    float* __restrict__ o2, float* __restrict__ o3,
    float* __restrict__ mlbuf)
{
  // 2 x (64 keys x 64 d) bf16 = 2 x 8 KB, XOR-swizzled: phys = log ^ ((row&7)<<4)
  __shared__ __align__(16) u16 kls[2][ACK * cHD];
  __shared__ u16 pbuf[4][16 * PLD];

  int t = threadIdx.x;
  int wave = t >> 6, lane = t & 63;
  int l15 = lane & 15, quad = lane >> 4;
  int qt = blockIdx.x, h = blockIdx.y;
  int bz = blockIdx.z;
  int b = bz & (cB - 1), split = bz >> 1;
  int q0 = qt * 64 + wave * 16;
  int kbase = split * KS;

  const u16* qp = Q + ((size_t)(b * cNH + h) * cS + q0) * cHD;
  const char* kp = (const char*)(K + ((size_t)(b * cNH + h) * cL + kbase) * cHD);
  const u16* vp = Vt + (size_t)(b * cNH + h) * cHD * cL + kbase;
  u16* pw = pbuf[wave];

  // staging geometry: thread covers phys bytes P0 and P0+4096 of the 8 KB tile;
  // source is pre-swizzled so swizzled reads see logical layout (involution).
  int P0 = wave * 1024 + lane * 16;
  int P1 = P0 + 4096;
  int s0 = P0 ^ (((P0 >> 7) & 7) << 4);
  int s1 = P1 ^ (((P1 >> 7) & 7) << 4);
  // swizzled fragment column offsets for ds_read_b128 (row&7 == l15&7)
  int fsw0 = (quad * 16) ^ ((l15 & 7) << 4);
  int fsw1 = (64 + quad * 16) ^ ((l15 & 7) << 4);

  s16x8 qf0 = ld_frag(qp + (size_t)l15 * cHD + quad * 8);
  s16x8 qf1 = ld_frag(qp + (size_t)l15 * cHD + 32 + quad * 8);

  // prologue: stage tile 0 into buffer 0
  gl_lds16((const u16*)(kp + s0), (u16*)((char*)&kls[0][0] + wave * 1024));
  gl_lds16((const u16*)(kp + s1), (u16*)((char*)&kls[0][0] + 4096 + wave * 1024));

  f32x4 oacc[4] = {};
  float mrow[4], lrow[4];
  #pragma unroll
  for (int i = 0; i < 4; i++) { mrow[i] = -1e30f; lrow[i] = 0.f; }

  constexpr float SCL = 0.125f * 1.4426950408889634f;

  for (int kt = 0; kt < NIT; kt++) {
    int cur = kt & 1;
    // ---- V loads for this tile (latency covered by QK+softmax below) ----
    uint4 vreg[8];
    #pragma unroll
    for (int dt = 0; dt < 4; dt++) {
      const u16* vr = vp + (size_t)(dt * 16 + l15) * cL + kt * ACK;
      vreg[2 * dt]     = *(const uint4*)(vr + quad * 8);
      vreg[2 * dt + 1] = *(const uint4*)(vr + 32 + quad * 8);
    }
    // ---- barrier A: all waves done reading kls[cur^1] (prev iter) ----
    asm volatile("" ::: "memory");
    __builtin_amdgcn_s_barrier();
    asm volatile("" ::: "memory");
    // ---- stage next tile into kls[cur^1] ----
    int nk = kt + 1; if (nk == NIT) nk = 0;
    const char* kn = kp + (size_t)nk * (ACK * cHD * 2);
    gl_lds16((const u16*)(kn + s0), (u16*)((char*)&kls[cur ^ 1][0] + wave * 1024));
    gl_lds16((const u16*)(kn + s1), (u16*)((char*)&kls[cur ^ 1][0] + 4096 + wave * 1024));
    // ---- wait own stage of tile kt (10 newer ops: 8 V + 2 stage-next) ----
    asm volatile("s_waitcnt vmcnt(10)" ::: "memory");
    __builtin_amdgcn_s_barrier();
    asm volatile("" ::: "memory");
    // ---- QK^T from LDS (swizzled reads, conflict-free) ----
    const char* kc = (const char*)&kls[cur][0];
    f32x4 sc[4];
    __builtin_amdgcn_s_setprio(1);
    #pragma unroll
    for (int nt = 0; nt < 4; nt++) {
      s16x8 kf0 = *(const s16x8*)(kc + (nt * 16 + l15) * 128 + fsw0);
      s16x8 kf1 = *(const s16x8*)(kc + (nt * 16 + l15) * 128 + fsw1);
      f32x4 a = {};
      a = __builtin_amdgcn_mfma_f32_16x16x32_bf16(qf0, kf0, a, 0, 0, 0);
      a = __builtin_amdgcn_mfma_f32_16x16x32_bf16(qf1, kf1, a, 0, 0, 0);
      sc[nt] = a * SCL;
    }
    __builtin_amdgcn_s_setprio(0);
    // ---- online softmax: DPP max-reduce (VALU pipe, no DS ops) ----
    float mx[4];
    #pragma unroll
    for (int i = 0; i < 4; i++)
      mx[i] = fmaxf(fmaxf(sc[0][i], sc[1][i]), fmaxf(sc[2][i], sc[3][i]));
    #pragma unroll
    for (int i = 0; i < 4; i++) {
      mx[i] = dpp_fmax<0xB1>(mx[i]);   // quad_perm xor1
      mx[i] = dpp_fmax<0x4E>(mx[i]);   // quad_perm xor2
      mx[i] = dpp_fmax<0x141>(mx[i]);  // row_half_mirror (xor7 in 8)
      mx[i] = dpp_fmax<0x140>(mx[i]);  // row_mirror (xor15 in 16)
    }
    bool need = (mx[0] > mrow[0]) | (mx[1] > mrow[1]) |
                (mx[2] > mrow[2]) | (mx[3] > mrow[3]);
    if (__any(need)) {
      float alpha[4];
      #pragma unroll
      for (int i = 0; i < 4; i++) {
        float mn = fmaxf(mrow[i], mx[i]);
        alpha[i] = exp2f(mrow[i] - mn);
        mrow[i] = mn;
        lrow[i] *= alpha[i];
      }
      #pragma unroll
      for (int dt = 0; dt < 4; dt++)
        #pragma unroll
        for (int i = 0; i < 4; i++) oacc[dt][i] *= alpha[i];
    }
    float ps[4] = {};
    #pragma unroll
    for (int nt = 0; nt < 4; nt++)
      #pragma unroll
      for (int i = 0; i < 4; i++) {
        float p = exp2f(sc[nt][i] - mrow[i]);
        ps[i] += p;
        pw[(quad * 4 + i) * PLD + nt * 16 + l15] = f2u_rt(p);
      }
    #pragma unroll
    for (int i = 0; i < 4; i++) lrow[i] += ps[i];   // per-lane partial; reduced once at end
    // ---- PV ----
    s16x8 pf0 = *(const s16x8*)&pw[l15 * PLD + quad * 8];
    s16x8 pf1 = *(const s16x8*)&pw[l15 * PLD + 32 + quad * 8];
    __builtin_amdgcn_s_setprio(1);
    #pragma unroll
    for (int dt = 0; dt < 4; dt++) {
      oacc[dt] = __builtin_amdgcn_mfma_f32_16x16x32_bf16(pf0, u4_frag(vreg[2 * dt]), oacc[dt], 0, 0, 0);
      oacc[dt] = __builtin_amdgcn_mfma_f32_16x16x32_bf16(pf1, u4_frag(vreg[2 * dt + 1]), oacc[dt], 0, 0, 0);
    }
    __builtin_amdgcn_s_setprio(0);
  }
  // ---- final l-reduce across the 16-lane key group ----
  #pragma unroll
  for (int off = 1; off < 16; off <<= 1)
    #pragma unroll
    for (int i = 0; i < 4; i++) lrow[i] += __shfl_xor(lrow[i], off);
  // ---- epilogue: unnormalized partial O + (m,l) ----
  float* ob = (split == 0) ? o0 : (split == 1) ? o1 : (split == 2) ? o2 : o3;
  #pragma unroll
  for (int i = 0; i < 4; i++) {
    int q = q0 + quad * 4 + i;
    size_t Rl = (size_t)(b * cNH + h) * cS + q;
    float* orow = ob + Rl * cHD;
    #pragma unroll
    for (int dt = 0; dt < 4; dt++)
      orow[dt * 16 + l15] = oacc[dt][i];
    if (l15 == 0) {
      mlbuf[((size_t)split * NRB + Rl) * 2] = mrow[i];
      mlbuf[((size_t)split * NRB + Rl) * 2 + 1] = lrow[i];
    }
  }
}

// ---------------- split-K merge: combine four softmax partials -> bf16 ctx ----------------
__global__ __launch_bounds__(256) void attn_merge(
    const float* __restrict__ o0, const float* __restrict__ o1,
    const float* __restrict__ o2, const float* __restrict__ o3,
    const float* __restrict__ mlbuf, u16* __restrict__ ctx)
{
  int t = threadIdx.x;
  int R = blockIdx.x * 4 + (t >> 6);   // (b*cNH+h)*cS + q
  int d = t & 63;
  float ms[KSPLIT], ls[KSPLIT];
  float m = -1e30f;
  #pragma unroll
  for (int s = 0; s < KSPLIT; s++) {
    ms[s] = mlbuf[((size_t)s * NRB + R) * 2];
    ls[s] = mlbuf[((size_t)s * NRB + R) * 2 + 1];
    m = fmaxf(m, ms[s]);
  }
  const float* ops[KSPLIT] = {o0, o1, o2, o3};
  float num = 0.f, den = 0.f;
  #pragma unroll
  for (int s = 0; s < KSPLIT; s++) {
    float a = exp2f(ms[s] - m);
    num += ops[s][(size_t)R * cHD + d] * a;
    den += ls[s] * a;
  }
  float val = num / den;
  int q = R & (cS - 1), h = (R >> 10) & 15, b = R >> 14;
  ctx[((size_t)b * cS + q) * cH + h * cHD + d] = f2u(val);
}

extern "C" void kernel_launch(void* const* d_in, const int* in_sizes, int n_in,
                              void* d_out, int out_size, void* d_ws, size_t ws_size,
                              hipStream_t stream)
{
  const float* hidden = (const float*)d_in[0];
  const float* cache  = (const float*)d_in[1];
  const float* ln_s   = (const float*)d_in[2];
  const float* ln_b   = (const float*)d_in[3];
  const float* Wq     = (const float*)d_in[4];
  const float* Wk     = (const float*)d_in[5];
  const float* Wv     = (const float*)d_in[6];
  const float* Wo     = (const float*)d_in[7];
  const float* gate   = (const float*)d_in[8];
  const float* lsc    = (const float*)d_in[9];
  float* outp = (float*)d_out;

  // ws: kvin 20.97M | vt 20.97M | opart(splits 0,1) 16.78M  (~58.7 MB)
  u16* kvin = (u16*)d_ws;
  u16* vt   = kvin + (size_t)cB * cL * cH;
  float* opart = (float*)(vt + (size_t)cB * cL * cH);
  float* o0 = opart;
  float* o1 = opart + (size_t)cB * cNH * cS * cHD;          // +8.39MB
  // aliases into kvin (dead rows by the time these are written):
  u16* qb  = kvin;                                // [0, 4.19M) written by Q GEMM (last kvin reader)
  u16* ctx = kvin + (size_t)2 * 1024 * 1024;      // [4.19M, 8.39M) written by attn_merge
  float* o2 = (float*)(kvin + (size_t)4 * 1024 * 1024);   // bytes [8.39M, 16.78M)
  float* mlbuf = (float*)(kvin + (size_t)8 * 1024 * 1024);// bytes [16.78M, 17.83M), 4 splits
  // split-3 opart parked in d_out output region [0, 8.39M) — written by attn,
  // read by merge, then overwritten by the step-7 GEMM epilogue:
  float* o3 = outp;
  // scratch parked in d_out (overwritten by memcpy/final-LN at the end):
  u16* kb = (u16*)(outp + (size_t)cB * cS * cH);
  u16* Wt = (u16*)(outp + (size_t)(1 + 3) * cB * cS * cH);
  u16* Wt_q = Wt;
  u16* Wt_k = Wt + (size_t)cH * cH;
  u16* Wt_v = Wt + (size_t)2 * cH * cH;
  u16* Wt_o = Wt + (size_t)3 * cH * cH;

  // 1) weight transpose+convert
  wtrans<<<dim3(32, 32, 4), 256, 0, stream>>>(Wq, Wk, Wv, Wo, Wt);
  // 2) cache -> kvin head rows (bf16, permuted)
  cache2kv<<<cB * cW * cS, 256, 0, stream>>>(cache, kvin);
  // 3) pre-norm -> kvin tail rows (bf16)
  ln_bf16<<<cB * cS, 256, 0, stream>>>(hidden, kvin, ln_s, ln_b);

  // 4) fused K|V projection (Wt_k,Wt_v contiguous -> one 2048-col GEMM), then Q
  mgemm<<<dim3(16, (cB * cL) / GBM), 256, 0, stream>>>(
      kvin, Wt_k, cL, 0, cL, cL, 5, kb, vt, nullptr, nullptr, nullptr, nullptr, nullptr);
  mgemm<<<dim3(8, (cB * cS) / GBM), 256, 0, stream>>>(
      kvin, Wt_q, cS, cW * cS, cL, cS, 1, qb, nullptr, nullptr, nullptr, nullptr, nullptr, nullptr);

  // 5) RoPE on Q and K
  rope_b16<<<(cB * cNH * cS * 32) / 256, 256, 0, stream>>>(qb, cS);
  rope_b16<<<(cB * cNH * cL * 32) / 256, 256, 0, stream>>>(kb, cL);

  // 6) 4-way split-K MFMA flash attention -> partials, then merge -> ctx (bf16)
  attn_mfma<<<dim3(cS / 64, cNH, cB * KSPLIT), 256, 0, stream>>>(
      qb, kb, vt, o0, o1, o2, o3, mlbuf);
  attn_merge<<<(cB * cNH * cS) / 4, 256, 0, stream>>>(o0, o1, o2, o3, mlbuf, ctx);

  // 7) ctx @ Wo with fused gated residual -> output f32
  mgemm<<<dim3(8, (cB * cS) / GBM), 256, 0, stream>>>(
      ctx, Wt_o, cB * cS, 0, cB * cS, cB * cS, 2, nullptr, nullptr,
      hidden, cache, gate, lsc, outp);

  // 8) new_cache[0:3] = cache[1:4]
  hipMemcpyAsync(outp + (size_t)cB * cS * cH, cache + (size_t)cB * cS * cH,
                 (size_t)(cW - 1) * cB * cS * cH * sizeof(float),
                 hipMemcpyDeviceToDevice, stream);
  // 9) final layernorm -> new_cache slot 3
  ln_f32<<<cB * cS, 256, 0, stream>>>(outp, outp + (size_t)cW * cB * cS * cH, ln_s, ln_b);
}

// Round 6
// 432.435 us; speedup vs baseline: 1.7757x; 1.1167x over previous
//
#include <hip/hip_runtime.h>
#include <math.h>

typedef unsigned short u16;

constexpr int cB = 2;
constexpr int cS = 1024;
constexpr int cH = 1024;
constexpr int cNH = 16;
constexpr int cHD = 64;
constexpr int cW = 4;
constexpr int cL = (cW + 1) * cS; // 5120
constexpr float cEPS = 1e-5f;

typedef short s16x8 __attribute__((ext_vector_type(8)));   // 8 bf16 (4 VGPRs)
typedef float f32x4 __attribute__((ext_vector_type(4)));   // MFMA C/D

__device__ __forceinline__ float u2f(u16 u) {
  union { unsigned int i; float f; } x; x.i = ((unsigned int)u) << 16; return x.f;
}
__device__ __forceinline__ u16 f2u(float f) {
  union { float f; unsigned int i; } x; x.f = f;
  unsigned int i = x.i;
  i += 0x7fffu + ((i >> 16) & 1u); // RNE
  return (u16)(i >> 16);
}
// fast path: native v_cvt bf16 (RNE), 1 VALU op
__device__ __forceinline__ u16 f2u_rt(float f) {
  union { __bf16 b; u16 u; } c; c.b = (__bf16)f; return c.u;
}
__device__ __forceinline__ s16x8 ld_frag(const u16* p) {
  uint4 v = *(const uint4*)p;
  union { uint4 u; s16x8 s; } c; c.u = v; return c.s;
}
__device__ __forceinline__ s16x8 u4_frag(uint4 v) {
  union { uint4 u; s16x8 s; } c; c.u = v; return c.s;
}
// async 16B global -> LDS (dest = wave-uniform base + lane*16)
__device__ __forceinline__ void gl_lds16(const u16* g, u16* l) {
  __builtin_amdgcn_global_load_lds(
      (const __attribute__((address_space(1))) unsigned int*)g,
      (__attribute__((address_space(3))) unsigned int*)l, 16, 0, 0);
}
// VALU-pipe cross-lane fmax via DPP (ctrl must be a literal -> template param)
template <int CTRL>
__device__ __forceinline__ float dpp_fmax(float x) {
  union { float f; int i; } a, r;
  a.f = x;
  r.i = __builtin_amdgcn_update_dpp(a.i, a.i, CTRL, 0xF, 0xF, true);
  return fmaxf(x, r.f);
}

// ---------------- LayerNorm f32 -> f32 (final LN) ----------------
__global__ __launch_bounds__(256) void ln_f32(
    const float* __restrict__ src, float* __restrict__ dst,
    const float* __restrict__ scale, const float* __restrict__ bias)
{
  int r = blockIdx.x;
  int t = threadIdx.x;
  const float* sp = src + (size_t)r * cH;
  float4 x = ((const float4*)sp)[t];
  float s1 = x.x + x.y + x.z + x.w;
  float s2 = x.x * x.x + x.y * x.y + x.z * x.z + x.w * x.w;
  #pragma unroll
  for (int off = 32; off > 0; off >>= 1) {
    s1 += __shfl_down(s1, off);
    s2 += __shfl_down(s2, off);
  }
  __shared__ float w1[4], w2[4];
  __shared__ float stat[2];
  int wid = t >> 6, lid = t & 63;
  if (lid == 0) { w1[wid] = s1; w2[wid] = s2; }
  __syncthreads();
  if (t == 0) {
    float a = w1[0] + w1[1] + w1[2] + w1[3];
    float b = w2[0] + w2[1] + w2[2] + w2[3];
    float mu = a * (1.f / cH);
    float var = b * (1.f / cH) - mu * mu;
    if (var < 0.f) var = 0.f;
    stat[0] = mu; stat[1] = rsqrtf(var + cEPS);
  }
  __syncthreads();
  float mu = stat[0], rs = stat[1];
  int h0 = t * 4;
  float4 sc = *(const float4*)(scale + h0);
  float4 bi = *(const float4*)(bias + h0);
  float4 o;
  o.x = (x.x - mu) * rs * sc.x + bi.x;
  o.y = (x.y - mu) * rs * sc.y + bi.y;
  o.z = (x.z - mu) * rs * sc.z + bi.z;
  o.w = (x.w - mu) * rs * sc.w + bi.w;
  *(float4*)(dst + (size_t)r * cH + h0) = o;
}

// ---------------- LayerNorm f32 -> bf16 into kvin tail ----------------
__global__ __launch_bounds__(256) void ln_bf16(
    const float* __restrict__ src, u16* __restrict__ kvin,
    const float* __restrict__ scale, const float* __restrict__ bias)
{
  int r = blockIdx.x;            // 0..cB*cS-1
  int t = threadIdx.x;
  const float* sp = src + (size_t)r * cH;
  float4 x = ((const float4*)sp)[t];
  float s1 = x.x + x.y + x.z + x.w;
  float s2 = x.x * x.x + x.y * x.y + x.z * x.z + x.w * x.w;
  #pragma unroll
  for (int off = 32; off > 0; off >>= 1) {
    s1 += __shfl_down(s1, off);
    s2 += __shfl_down(s2, off);
  }
  __shared__ float w1[4], w2[4];
  __shared__ float stat[2];
  int wid = t >> 6, lid = t & 63;
  if (lid == 0) { w1[wid] = s1; w2[wid] = s2; }
  __syncthreads();
  if (t == 0) {
    float a = w1[0] + w1[1] + w1[2] + w1[3];
    float b = w2[0] + w2[1] + w2[2] + w2[3];
    float mu = a * (1.f / cH);
    float var = b * (1.f / cH) - mu * mu;
    if (var < 0.f) var = 0.f;
    stat[0] = mu; stat[1] = rsqrtf(var + cEPS);
  }
  __syncthreads();
  float mu = stat[0], rs = stat[1];
  int h0 = t * 4;
  float4 sc = *(const float4*)(scale + h0);
  float4 bi = *(const float4*)(bias + h0);
  int b = r >> 10, s = r & (cS - 1);
  u16* dp = kvin + ((size_t)(b * cL + cW * cS + s)) * cH + h0;
  ushort4 o; u16* op = (u16*)&o;
  op[0] = f2u((x.x - mu) * rs * sc.x + bi.x);
  op[1] = f2u((x.y - mu) * rs * sc.y + bi.y);
  op[2] = f2u((x.z - mu) * rs * sc.z + bi.z);
  op[3] = f2u((x.w - mu) * rs * sc.w + bi.w);
  *(ushort4*)dp = o;
}

// -------- cache f32 [W,B,S,H] -> kvin bf16 [B, w*S+s, H] --------
__global__ __launch_bounds__(256) void cache2kv(const float* __restrict__ cache,
                                                u16* __restrict__ kvin) {
  int blk = blockIdx.x;          // cB*cW*cS = 8192
  int b = blk >> 12, w = (blk >> 10) & 3, s = blk & 1023;
  const float* src = cache + ((size_t)((w * cB + b) * cS + s)) * cH;
  u16* dst = kvin + ((size_t)(b * cL + w * cS + s)) * cH;
  int t = threadIdx.x;
  float4 v = *(const float4*)(src + t * 4);
  ushort4 o; u16* op = (u16*)&o;
  op[0] = f2u(v.x); op[1] = f2u(v.y); op[2] = f2u(v.z); op[3] = f2u(v.w);
  *(ushort4*)(dst + t * 4) = o;
}

// -------- weight transpose: W f32 [k][n] -> Wt bf16 [n][k], 4 matrices --------
__global__ __launch_bounds__(256) void wtrans(
    const float* __restrict__ W0, const float* __restrict__ W1,
    const float* __restrict__ W2, const float* __restrict__ W3,
    u16* __restrict__ Wt)
{
  __shared__ float tile[32][33];
  int mat = blockIdx.z;
  const float* W = (mat == 0) ? W0 : (mat == 1) ? W1 : (mat == 2) ? W2 : W3;
  u16* out = Wt + (size_t)mat * cH * cH;
  int k0 = blockIdx.y * 32, n0 = blockIdx.x * 32;
  int t = threadIdx.x;
  int r = t >> 3, c = (t & 7) * 4;
  float4 v = *(const float4*)(W + (size_t)(k0 + r) * cH + n0 + c);
  tile[r][c] = v.x; tile[r][c + 1] = v.y; tile[r][c + 2] = v.z; tile[r][c + 3] = v.w;
  __syncthreads();
  ushort4 o; u16* op = (u16*)&o;
  #pragma unroll
  for (int j = 0; j < 4; j++) op[j] = f2u(tile[c + j][r]);
  *(ushort4*)(out + (size_t)(n0 + r) * cH + k0 + c) = o;
}

// ---------------- MFMA GEMM: C[M,1024] = A(bf16)[M,1024] @ W, Wt=[n][k] bf16 ----------------
// K-loop: m97-style — global_load_lds(16B) direct into linear [128][32] LDS
// tiles, double-buffered, counted vmcnt(4), raw barriers (pattern proven in
// attn_mfma since round 2).  Epilogues unchanged.
// mode 5: fused K|V projection — Wt spans 2048 rows (Wk then Wv); n0<1024 -> K
// epilogue (mode1 -> Cb), n0>=1024 -> V epilogue (mode3 -> Cb2, n-1024).
constexpr int GBM = 128, GBN = 128, TLD = 136;

__global__ __launch_bounds__(256) void mgemm(
    const u16* __restrict__ A, const u16* __restrict__ Wt,
    int a_rpb, int a_base, int a_stride,
    int c_rpb, int mode,
    u16* __restrict__ Cb, u16* __restrict__ Cb2,
    const float* __restrict__ hidden, const float* __restrict__ cachefull,
    const float* __restrict__ gate, const float* __restrict__ lsc,
    float* __restrict__ outp)
{
  // 17408 u16 = 34.8 KB; staging dbuf occupies the first 16384 u16 (32 KB):
  //   A buf0 @0, A buf1 @4096, B buf0 @8192, B buf1 @12288  (each [128][32] u16)
  // mode-3 epilogue reuses the whole thing as t2[128][TLD] after a vmcnt(0) drain.
  __shared__ __align__(16) u16 smem[128 * TLD];

  int t = threadIdx.x;
  int m0 = blockIdx.y * GBM, n0 = blockIdx.x * GBN;
  int wave = t >> 6, lane = t & 63, l15 = lane & 15, quad = lane >> 4;
  int wm = (wave >> 1) * 64, wn = (wave & 1) * 64;

  // staging source pointers: thread t covers row (t>>2), bytes (t&3)*16 of a
  // 64B row-chunk; dest = linear LDS byte t*16 (wave-uniform base + lane*16).
  int sr = t >> 2, sk = (t & 3) * 8;
  int rg0 = m0 + sr, rg1 = rg0 + 64;
  int ab0 = rg0 / a_rpb, ab1 = rg1 / a_rpb;
  const u16* arow0 = A + (size_t)(ab0 * a_stride + a_base + (rg0 - ab0 * a_rpb)) * cH + sk;
  const u16* arow1 = A + (size_t)(ab1 * a_stride + a_base + (rg1 - ab1 * a_rpb)) * cH + sk;
  const u16* wrow0 = Wt + (size_t)(n0 + sr) * cH + sk;
  const u16* wrow1 = Wt + (size_t)(n0 + sr + 64) * cH + sk;

  u16* As0 = smem;
  u16* Bs0 = smem + 8192;
  int wofs = wave * 512;       // u16; wave-uniform dest base within half-tile

  f32x4 acc[4][4] = {};

  // prologue: stage tile 0 into buffer 0
  gl_lds16(arow0, As0 + wofs);
  gl_lds16(arow1, As0 + 2048 + wofs);
  gl_lds16(wrow0, Bs0 + wofs);
  gl_lds16(wrow1, Bs0 + 2048 + wofs);

  constexpr int NK = cH / 32;  // 32 K-steps
  for (int kt = 0; kt < NK; kt++) {
    int cur = kt & 1;
    // barrier A: all waves done reading buf cur^1 (previous iteration)
    asm volatile("" ::: "memory");
    __builtin_amdgcn_s_barrier();
    asm volatile("" ::: "memory");
    // prefetch next tile into buf cur^1
    int nk = kt + 1; if (nk == NK) nk = 0;
    int nko = nk * 32;
    u16* Abn = As0 + (cur ^ 1) * 4096;
    u16* Bbn = Bs0 + (cur ^ 1) * 4096;
    gl_lds16(arow0 + nko, Abn + wofs);
    gl_lds16(arow1 + nko, Abn + 2048 + wofs);
    gl_lds16(wrow0 + nko, Bbn + wofs);
    gl_lds16(wrow1 + nko, Bbn + 2048 + wofs);
    // wait own stage of tile kt (4 newer outstanding = the prefetch just issued)
    asm volatile("s_waitcnt vmcnt(4)" ::: "memory");
    __builtin_amdgcn_s_barrier();
    asm volatile("" ::: "memory");
    // fragments from buf cur (linear [128][32], row stride 64B)
    const u16* Ab = As0 + cur * 4096;
    const u16* Bb = Bs0 + cur * 4096;
    s16x8 af[4], bf[4];
    #pragma unroll
    for (int mt = 0; mt < 4; mt++)
      af[mt] = *(const s16x8*)&Ab[(wm + mt * 16 + l15) * 32 + quad * 8];
    #pragma unroll
    for (int nt = 0; nt < 4; nt++)
      bf[nt] = *(const s16x8*)&Bb[(wn + nt * 16 + l15) * 32 + quad * 8];
    #pragma unroll
    for (int mt = 0; mt < 4; mt++)
      #pragma unroll
      for (int nt = 0; nt < 4; nt++)
        acc[mt][nt] = __builtin_amdgcn_mfma_f32_16x16x32_bf16(af[mt], bf[nt], acc[mt][nt], 0, 0, 0);
  }

  int mode_eff = mode;
  u16* Cout = Cb;
  int nbase = n0;
  if (mode == 5) {
    if (n0 < cH) { mode_eff = 1; }
    else { mode_eff = 3; Cout = Cb2; nbase = n0 - cH; }
  }

  if (mode_eff == 1) {
    #pragma unroll
    for (int mt = 0; mt < 4; mt++)
      #pragma unroll
      for (int i = 0; i < 4; i++) {
        int rg = m0 + wm + mt * 16 + quad * 4 + i;
        int bo = rg / c_rpb, lo = rg - bo * c_rpb;
        #pragma unroll
        for (int nt = 0; nt < 4; nt++) {
          int n = nbase + wn + nt * 16 + l15;
          int h = n >> 6, d = n & 63;
          Cout[(((size_t)(bo * cNH + h) * c_rpb + lo) * cHD) + d] = f2u(acc[mt][nt][i]);
        }
      }
  } else if (mode_eff == 3) {
    u16* t2 = smem;
    // drain wrap-around prefetch before reusing LDS
    asm volatile("s_waitcnt vmcnt(0)" ::: "memory");
    __syncthreads();
    #pragma unroll
    for (int mt = 0; mt < 4; mt++)
      #pragma unroll
      for (int nt = 0; nt < 4; nt++) {
        ushort4 o; u16* op = (u16*)&o;
        #pragma unroll
        for (int i = 0; i < 4; i++) op[i] = f2u(acc[mt][nt][i]);
        *(ushort4*)&t2[(size_t)(wn + nt * 16 + l15) * TLD + wm + mt * 16 + quad * 4] = o;
      }
    __syncthreads();
    int n_l = t >> 1, mh = (t & 1) * 64;
    int bo = m0 / c_rpb;
    int lo = m0 - bo * c_rpb + mh;
    int n = nbase + n_l, h = n >> 6, d = n & 63;
    u16* dst = Cout + ((size_t)(bo * cNH + h) * cHD + d) * (size_t)c_rpb + lo;
    #pragma unroll
    for (int j = 0; j < 8; j++)
      *(uint4*)(dst + j * 8) = *(const uint4*)&t2[(size_t)n_l * TLD + mh + j * 8];
  } else {
    float gv[4], lv[4];
    #pragma unroll
    for (int nt = 0; nt < 4; nt++) {
      int n = n0 + wn + nt * 16 + l15;
      gv[nt] = 1.f / (1.f + __expf(-gate[n]));
      lv[nt] = lsc[n];
    }
    #pragma unroll
    for (int mt = 0; mt < 4; mt++)
      #pragma unroll
      for (int i = 0; i < 4; i++) {
        int rg = m0 + wm + mt * 16 + quad * 4 + i;
        size_t rbase = (size_t)rg * cH;
        #pragma unroll
        for (int nt = 0; nt < 4; nt++) {
          int n = n0 + wn + nt * 16 + l15;
          float hid = hidden[rbase + n];
          float cr = cachefull[(size_t)3 * cB * cS * cH + rbase + n];
          outp[rbase + n] = hid + lv[nt] * (gv[nt] * acc[mt][nt][i] + (1.f - gv[nt]) * cr);
        }
      }
  }
}

// ---------------- RoPE in-place on head-major bf16 [b*h][rows][64] ----------------
__global__ __launch_bounds__(256) void rope_b16(u16* __restrict__ X, int rows) {
  size_t idx = (size_t)blockIdx.x * 256 + threadIdx.x;
  int d = (int)(idx & 31);
  size_t rest = idx >> 5;
  int row = (int)(rest % rows);
  size_t bh = rest / rows;
  u16* xp = X + (bh * rows + row) * cHD;
  int pos = row & (cS - 1);
  float freq = exp2f(-(float)d * (13.287712379549449f / 32.f)); // 10000^(-d/32)
  float ang = (float)pos * freq;
  float sn, cs;
  sincosf(ang, &sn, &cs);
  float x1 = u2f(xp[d]), x2 = u2f(xp[d + 32]);
  xp[d] = f2u(x1 * cs - x2 * sn);
  xp[d + 32] = f2u(x1 * sn + x2 * cs);
}

// ---------------- MFMA flash attention, split-K over key quarters ----------------
// K tiles staged in LDS (double-buffered, XOR-swizzled, global_load_lds,
// counted vmcnt, raw barriers).  All 4 waves of a block share the K tile.
constexpr int ACK = 64;
constexpr int PLD = 72;
constexpr int KSPLIT = 4;
constexpr int KS = cL / KSPLIT;      // 1280 keys per split
constexpr int NIT = KS / ACK;        // 20 tiles
constexpr int NRB = cB * cNH * cS;   // rows per split (32768)

__global__ __launch_bounds__(256, 4) void attn_mfma(
    const u16* __restrict__ Q, const u16* __restrict__ K, const u16* __restrict__ Vt,
    float* __restrict__ o0, float* __restrict__ o1,
    float* __restrict__ o2, float* __restrict__ o3,
    float* __restrict__ mlbuf)
{
  // 2 x (64 keys x 64 d) bf16 = 2 x 8 KB, XOR-swizzled: phys = log ^ ((row&7)<<4)
  __shared__ __align__(16) u16 kls[2][ACK * cHD];
  __shared__ u16 pbuf[4][16 * PLD];

  int t = threadIdx.x;
  int wave = t >> 6, lane = t & 63;
  int l15 = lane & 15, quad = lane >> 4;
  int qt = blockIdx.x, h = blockIdx.y;
  int bz = blockIdx.z;
  int b = bz & (cB - 1), split = bz >> 1;
  int q0 = qt * 64 + wave * 16;
  int kbase = split * KS;

  const u16* qp = Q + ((size_t)(b * cNH + h) * cS + q0) * cHD;
  const char* kp = (const char*)(K + ((size_t)(b * cNH + h) * cL + kbase) * cHD);
  const u16* vp = Vt + (size_t)(b * cNH + h) * cHD * cL + kbase;
  u16* pw = pbuf[wave];

  // staging geometry: thread covers phys bytes P0 and P0+4096 of the 8 KB tile;
  // source is pre-swizzled so swizzled reads see logical layout (involution).
  int P0 = wave * 1024 + lane * 16;
  int P1 = P0 + 4096;
  int s0 = P0 ^ (((P0 >> 7) & 7) << 4);
  int s1 = P1 ^ (((P1 >> 7) & 7) << 4);
  // swizzled fragment column offsets for ds_read_b128 (row&7 == l15&7)
  int fsw0 = (quad * 16) ^ ((l15 & 7) << 4);
  int fsw1 = (64 + quad * 16) ^ ((l15 & 7) << 4);

  s16x8 qf0 = ld_frag(qp + (size_t)l15 * cHD + quad * 8);
  s16x8 qf1 = ld_frag(qp + (size_t)l15 * cHD + 32 + quad * 8);

  // prologue: stage tile 0 into buffer 0
  gl_lds16((const u16*)(kp + s0), (u16*)((char*)&kls[0][0] + wave * 1024));
  gl_lds16((const u16*)(kp + s1), (u16*)((char*)&kls[0][0] + 4096 + wave * 1024));

  f32x4 oacc[4] = {};
  float mrow[4], lrow[4];
  #pragma unroll
  for (int i = 0; i < 4; i++) { mrow[i] = -1e30f; lrow[i] = 0.f; }

  constexpr float SCL = 0.125f * 1.4426950408889634f;

  for (int kt = 0; kt < NIT; kt++) {
    int cur = kt & 1;
    // ---- V loads for this tile (latency covered by QK+softmax below) ----
    uint4 vreg[8];
    #pragma unroll
    for (int dt = 0; dt < 4; dt++) {
      const u16* vr = vp + (size_t)(dt * 16 + l15) * cL + kt * ACK;
      vreg[2 * dt]     = *(const uint4*)(vr + quad * 8);
      vreg[2 * dt + 1] = *(const uint4*)(vr + 32 + quad * 8);
    }
    // ---- barrier A: all waves done reading kls[cur^1] (prev iter) ----
    asm volatile("" ::: "memory");
    __builtin_amdgcn_s_barrier();
    asm volatile("" ::: "memory");
    // ---- stage next tile into kls[cur^1] ----
    int nk = kt + 1; if (nk == NIT) nk = 0;
    const char* kn = kp + (size_t)nk * (ACK * cHD * 2);
    gl_lds16((const u16*)(kn + s0), (u16*)((char*)&kls[cur ^ 1][0] + wave * 1024));
    gl_lds16((const u16*)(kn + s1), (u16*)((char*)&kls[cur ^ 1][0] + 4096 + wave * 1024));
    // ---- wait own stage of tile kt (10 newer ops: 8 V + 2 stage-next) ----
    asm volatile("s_waitcnt vmcnt(10)" ::: "memory");
    __builtin_amdgcn_s_barrier();
    asm volatile("" ::: "memory");
    // ---- QK^T from LDS (swizzled reads, conflict-free) ----
    const char* kc = (const char*)&kls[cur][0];
    f32x4 sc[4];
    __builtin_amdgcn_s_setprio(1);
    #pragma unroll
    for (int nt = 0; nt < 4; nt++) {
      s16x8 kf0 = *(const s16x8*)(kc + (nt * 16 + l15) * 128 + fsw0);
      s16x8 kf1 = *(const s16x8*)(kc + (nt * 16 + l15) * 128 + fsw1);
      f32x4 a = {};
      a = __builtin_amdgcn_mfma_f32_16x16x32_bf16(qf0, kf0, a, 0, 0, 0);
      a = __builtin_amdgcn_mfma_f32_16x16x32_bf16(qf1, kf1, a, 0, 0, 0);
      sc[nt] = a * SCL;
    }
    __builtin_amdgcn_s_setprio(0);
    // ---- online softmax: DPP max-reduce (VALU pipe, no DS ops) ----
    float mx[4];
    #pragma unroll
    for (int i = 0; i < 4; i++)
      mx[i] = fmaxf(fmaxf(sc[0][i], sc[1][i]), fmaxf(sc[2][i], sc[3][i]));
    #pragma unroll
    for (int i = 0; i < 4; i++) {
      mx[i] = dpp_fmax<0xB1>(mx[i]);   // quad_perm xor1
      mx[i] = dpp_fmax<0x4E>(mx[i]);   // quad_perm xor2
      mx[i] = dpp_fmax<0x141>(mx[i]);  // row_half_mirror (xor7 in 8)
      mx[i] = dpp_fmax<0x140>(mx[i]);  // row_mirror (xor15 in 16)
    }
    bool need = (mx[0] > mrow[0]) | (mx[1] > mrow[1]) |
                (mx[2] > mrow[2]) | (mx[3] > mrow[3]);
    if (__any(need)) {
      float alpha[4];
      #pragma unroll
      for (int i = 0; i < 4; i++) {
        float mn = fmaxf(mrow[i], mx[i]);
        alpha[i] = exp2f(mrow[i] - mn);
        mrow[i] = mn;
        lrow[i] *= alpha[i];
      }
      #pragma unroll
      for (int dt = 0; dt < 4; dt++)
        #pragma unroll
        for (int i = 0; i < 4; i++) oacc[dt][i] *= alpha[i];
    }
    float ps[4] = {};
    #pragma unroll
    for (int nt = 0; nt < 4; nt++)
      #pragma unroll
      for (int i = 0; i < 4; i++) {
        float p = exp2f(sc[nt][i] - mrow[i]);
        ps[i] += p;
        pw[(quad * 4 + i) * PLD + nt * 16 + l15] = f2u_rt(p);
      }
    #pragma unroll
    for (int i = 0; i < 4; i++) lrow[i] += ps[i];   // per-lane partial; reduced once at end
    // ---- PV ----
    s16x8 pf0 = *(const s16x8*)&pw[l15 * PLD + quad * 8];
    s16x8 pf1 = *(const s16x8*)&pw[l15 * PLD + 32 + quad * 8];
    __builtin_amdgcn_s_setprio(1);
    #pragma unroll
    for (int dt = 0; dt < 4; dt++) {
      oacc[dt] = __builtin_amdgcn_mfma_f32_16x16x32_bf16(pf0, u4_frag(vreg[2 * dt]), oacc[dt], 0, 0, 0);
      oacc[dt] = __builtin_amdgcn_mfma_f32_16x16x32_bf16(pf1, u4_frag(vreg[2 * dt + 1]), oacc[dt], 0, 0, 0);
    }
    __builtin_amdgcn_s_setprio(0);
  }
  // ---- final l-reduce across the 16-lane key group ----
  #pragma unroll
  for (int off = 1; off < 16; off <<= 1)
    #pragma unroll
    for (int i = 0; i < 4; i++) lrow[i] += __shfl_xor(lrow[i], off);
  // ---- epilogue: unnormalized partial O + (m,l) ----
  float* ob = (split == 0) ? o0 : (split == 1) ? o1 : (split == 2) ? o2 : o3;
  #pragma unroll
  for (int i = 0; i < 4; i++) {
    int q = q0 + quad * 4 + i;
    size_t Rl = (size_t)(b * cNH + h) * cS + q;
    float* orow = ob + Rl * cHD;
    #pragma unroll
    for (int dt = 0; dt < 4; dt++)
      orow[dt * 16 + l15] = oacc[dt][i];
    if (l15 == 0) {
      mlbuf[((size_t)split * NRB + Rl) * 2] = mrow[i];
      mlbuf[((size_t)split * NRB + Rl) * 2 + 1] = lrow[i];
    }
  }
}

// ---------------- split-K merge: combine four softmax partials -> bf16 ctx ----------------
__global__ __launch_bounds__(256) void attn_merge(
    const float* __restrict__ o0, const float* __restrict__ o1,
    const float* __restrict__ o2, const float* __restrict__ o3,
    const float* __restrict__ mlbuf, u16* __restrict__ ctx)
{
  int t = threadIdx.x;
  int R = blockIdx.x * 4 + (t >> 6);   // (b*cNH+h)*cS + q
  int d = t & 63;
  float ms[KSPLIT], ls[KSPLIT];
  float m = -1e30f;
  #pragma unroll
  for (int s = 0; s < KSPLIT; s++) {
    ms[s] = mlbuf[((size_t)s * NRB + R) * 2];
    ls[s] = mlbuf[((size_t)s * NRB + R) * 2 + 1];
    m = fmaxf(m, ms[s]);
  }
  const float* ops[KSPLIT] = {o0, o1, o2, o3};
  float num = 0.f, den = 0.f;
  #pragma unroll
  for (int s = 0; s < KSPLIT; s++) {
    float a = exp2f(ms[s] - m);
    num += ops[s][(size_t)R * cHD + d] * a;
    den += ls[s] * a;
  }
  float val = num / den;
  int q = R & (cS - 1), h = (R >> 10) & 15, b = R >> 14;
  ctx[((size_t)b * cS + q) * cH + h * cHD + d] = f2u(val);
}

extern "C" void kernel_launch(void* const* d_in, const int* in_sizes, int n_in,
                              void* d_out, int out_size, void* d_ws, size_t ws_size,
                              hipStream_t stream)
{
  const float* hidden = (const float*)d_in[0];
  const float* cache  = (const float*)d_in[1];
  const float* ln_s   = (const float*)d_in[2];
  const float* ln_b   = (const float*)d_in[3];
  const float* Wq     = (const float*)d_in[4];
  const float* Wk     = (const float*)d_in[5];
  const float* Wv     = (const float*)d_in[6];
  const float* Wo     = (const float*)d_in[7];
  const float* gate   = (const float*)d_in[8];
  const float* lsc    = (const float*)d_in[9];
  float* outp = (float*)d_out;

  // ws: kvin 20.97M | vt 20.97M | opart(splits 0,1) 16.78M  (~58.7 MB)
  u16* kvin = (u16*)d_ws;
  u16* vt   = kvin + (size_t)cB * cL * cH;
  float* opart = (float*)(vt + (size_t)cB * cL * cH);
  float* o0 = opart;
  float* o1 = opart + (size_t)cB * cNH * cS * cHD;          // +8.39MB
  // aliases into kvin (dead rows by the time these are written):
  u16* qb  = kvin;                                // [0, 4.19M) written by Q GEMM (last kvin reader)
  u16* ctx = kvin + (size_t)2 * 1024 * 1024;      // [4.19M, 8.39M) written by attn_merge
  float* o2 = (float*)(kvin + (size_t)4 * 1024 * 1024);   // bytes [8.39M, 16.78M)
  float* mlbuf = (float*)(kvin + (size_t)8 * 1024 * 1024);// bytes [16.78M, 17.83M), 4 splits
  // split-3 opart parked in d_out output region [0, 8.39M) — written by attn,
  // read by merge, then overwritten by the step-7 GEMM epilogue:
  float* o3 = outp;
  // scratch parked in d_out (overwritten by memcpy/final-LN at the end):
  u16* kb = (u16*)(outp + (size_t)cB * cS * cH);
  u16* Wt = (u16*)(outp + (size_t)(1 + 3) * cB * cS * cH);
  u16* Wt_q = Wt;
  u16* Wt_k = Wt + (size_t)cH * cH;
  u16* Wt_v = Wt + (size_t)2 * cH * cH;
  u16* Wt_o = Wt + (size_t)3 * cH * cH;

  // 1) weight transpose+convert
  wtrans<<<dim3(32, 32, 4), 256, 0, stream>>>(Wq, Wk, Wv, Wo, Wt);
  // 2) cache -> kvin head rows (bf16, permuted)
  cache2kv<<<cB * cW * cS, 256, 0, stream>>>(cache, kvin);
  // 3) pre-norm -> kvin tail rows (bf16)
  ln_bf16<<<cB * cS, 256, 0, stream>>>(hidden, kvin, ln_s, ln_b);

  // 4) fused K|V projection (Wt_k,Wt_v contiguous -> one 2048-col GEMM), then Q
  mgemm<<<dim3(16, (cB * cL) / GBM), 256, 0, stream>>>(
      kvin, Wt_k, cL, 0, cL, cL, 5, kb, vt, nullptr, nullptr, nullptr, nullptr, nullptr);
  mgemm<<<dim3(8, (cB * cS) / GBM), 256, 0, stream>>>(
      kvin, Wt_q, cS, cW * cS, cL, cS, 1, qb, nullptr, nullptr, nullptr, nullptr, nullptr, nullptr);

  // 5) RoPE on Q and K
  rope_b16<<<(cB * cNH * cS * 32) / 256, 256, 0, stream>>>(qb, cS);
  rope_b16<<<(cB * cNH * cL * 32) / 256, 256, 0, stream>>>(kb, cL);

  // 6) 4-way split-K MFMA flash attention -> partials, then merge -> ctx (bf16)
  attn_mfma<<<dim3(cS / 64, cNH, cB * KSPLIT), 256, 0, stream>>>(
      qb, kb, vt, o0, o1, o2, o3, mlbuf);
  attn_merge<<<(cB * cNH * cS) / 4, 256, 0, stream>>>(o0, o1, o2, o3, mlbuf, ctx);

  // 7) ctx @ Wo with fused gated residual -> output f32
  mgemm<<<dim3(8, (cB * cS) / GBM), 256, 0, stream>>>(
      ctx, Wt_o, cB * cS, 0, cB * cS, cB * cS, 2, nullptr, nullptr,
      hidden, cache, gate, lsc, outp);

  // 8) new_cache[0:3] = cache[1:4]
  hipMemcpyAsync(outp + (size_t)cB * cS * cH, cache + (size_t)cB * cS * cH,
                 (size_t)(cW - 1) * cB * cS * cH * sizeof(float),
                 hipMemcpyDeviceToDevice, stream);
  // 9) final layernorm -> new_cache slot 3
  ln_f32<<<cB * cS, 256, 0, stream>>>(outp, outp + (size_t)cW * cB * cS * cH, ln_s, ln_b);
}